// Round 1
// baseline (442.895 us; speedup 1.0000x reference)
//
#include <hip/hip_runtime.h>
#include <hip/hip_bf16.h>
#include <stdint.h>

// B=2, T=2048, D=2048, NH=16, NKV=4, HD=128.  qkv width = 3072 (q 0..2047, k 2048..2559, v 2560..3071)

typedef __attribute__((ext_vector_type(8))) short short8;
typedef __attribute__((ext_vector_type(4))) float f32x4;

#define GLOAD16(gp, lp) \
  __builtin_amdgcn_global_load_lds((const __attribute__((address_space(1))) void*)(gp), \
                                   (__attribute__((address_space(3))) void*)(lp), 16, 0, 0)

__device__ __forceinline__ float bf2f(unsigned short u) {
  union { unsigned int i; float f; } v; v.i = ((unsigned int)u) << 16; return v.f;
}
__device__ __forceinline__ unsigned short f2bf(float f) {
  union { float fl; unsigned int i; } v; v.fl = f;
  unsigned int r = v.i + 0x7fffu + ((v.i >> 16) & 1u);
  return (unsigned short)(r >> 16);
}

// ---------------- prep: f32->bf16 conversions + rope tables ----------------
__global__ __launch_bounds__(256) void prep_kernel(
    const float* __restrict__ x, const float* __restrict__ qw,
    const float* __restrict__ kw, const float* __restrict__ vw,
    const float* __restrict__ ow,
    unsigned short* __restrict__ xb, unsigned short* __restrict__ wqkv,
    unsigned short* __restrict__ owb, float* __restrict__ cost, float* __restrict__ sint) {
  const int NX = 2097152;   // x elems/4
  const int NW = 1572864;   // wqkv elems/4
  const int NO = 1048576;   // ow elems/4
  const int NT = 131072;    // table entries (2048*64)
  int tid = blockIdx.x * 256 + threadIdx.x;
  if (tid < NX) {
    float4 v = ((const float4*)x)[tid];
    uint2 o; o.x = (unsigned)f2bf(v.x) | ((unsigned)f2bf(v.y) << 16);
    o.y = (unsigned)f2bf(v.z) | ((unsigned)f2bf(v.w) << 16);
    ((uint2*)xb)[tid] = o;
  } else if (tid < NX + NW) {
    int i = tid - NX; int e = i * 4;
    const float* src = (e < 4194304) ? (qw + e)
                     : (e < 5242880) ? (kw + (e - 4194304))
                                     : (vw + (e - 5242880));
    float4 v = *(const float4*)src;
    uint2 o; o.x = (unsigned)f2bf(v.x) | ((unsigned)f2bf(v.y) << 16);
    o.y = (unsigned)f2bf(v.z) | ((unsigned)f2bf(v.w) << 16);
    ((uint2*)wqkv)[i] = o;
  } else if (tid < NX + NW + NO) {
    int i = tid - NX - NW;
    float4 v = ((const float4*)ow)[i];
    uint2 o; o.x = (unsigned)f2bf(v.x) | ((unsigned)f2bf(v.y) << 16);
    o.y = (unsigned)f2bf(v.z) | ((unsigned)f2bf(v.w) << 16);
    ((uint2*)owb)[i] = o;
  } else if (tid < NX + NW + NO + NT) {
    int i = tid - NX - NW - NO;
    int t = i >> 6, j = i & 63;
    // T(2048) > TSL(1024) branch: inv = 1/(10000 * 2^((128/126)^(j/64)))
    float e = exp2f(0.02272008f * (float)j * (1.0f / 64.0f));   // (128/126)^(j/64)
    float inv = 1.0f / (10000.0f * exp2f(e));
    float f = (float)t * inv;
    cost[i] = cosf(f);
    sint[i] = sinf(f);
  }
}

// ---------------- GEMM C = A @ Bw^T   (A[M][K], Bw[N][K], bf16 in, bf16/f32 out) ----
// 128x128 tile, BK=64, 4 waves, m97 structure; XOR-swizzled LDS (pre-swizzled source).
template <int OUTF>  // 0 = bf16 out, 1 = f32 out
__global__ __launch_bounds__(256) void gemm_bt(const unsigned short* __restrict__ A,
                                               const unsigned short* __restrict__ Bw,
                                               void* __restrict__ Cp,
                                               int M, int N, int K) {
  __shared__ unsigned short a_sm[128 * 64];
  __shared__ unsigned short b_sm[128 * 64];
  const int tid = threadIdx.x;
  const int l = tid & 63, w = tid >> 6;
  const int lane_r = l & 15, lane_g = l >> 4;
  const int wr = w >> 1, wc = w & 1;
  const int m0 = blockIdx.y * 128, n0 = blockIdx.x * 128;

  f32x4 acc[4][4];
#pragma unroll
  for (int i = 0; i < 4; ++i)
#pragma unroll
    for (int j = 0; j < 4; ++j) acc[i][j] = {0.f, 0.f, 0.f, 0.f};

  // staging descriptors: 1024 chunks (16B) per operand tile; row = idx>>3, c = idx&7
  const unsigned short* gA[4]; const unsigned short* gB[4];
  unsigned short* lA[4]; unsigned short* lB[4];
#pragma unroll
  for (int t = 0; t < 4; ++t) {
    int idx = t * 256 + tid;
    int row = idx >> 3, c = idx & 7;
    int gc = c ^ (row & 7);               // inverse-swizzled global source
    gA[t] = A + (size_t)(m0 + row) * K + gc * 8;
    gB[t] = Bw + (size_t)(n0 + row) * K + gc * 8;
    lA[t] = &a_sm[idx * 8];
    lB[t] = &b_sm[idx * 8];
  }
  // fragment read offsets (swizzled), loop-invariant
  int oA[2][4], oB[2][4];
#pragma unroll
  for (int ks = 0; ks < 2; ++ks)
#pragma unroll
    for (int i = 0; i < 4; ++i) {
      int ra = wr * 64 + i * 16 + lane_r;
      oA[ks][i] = ((ra * 64 + ks * 32 + lane_g * 8) * 2) ^ ((ra & 7) << 4);
      int rb = wc * 64 + i * 16 + lane_r;
      oB[ks][i] = ((rb * 64 + ks * 32 + lane_g * 8) * 2) ^ ((rb & 7) << 4);
    }

  for (int kt = 0; kt < K; kt += 64) {
#pragma unroll
    for (int t = 0; t < 4; ++t) {
      GLOAD16(gA[t] + kt, lA[t]);
      GLOAD16(gB[t] + kt, lB[t]);
    }
    __syncthreads();
#pragma unroll
    for (int ks = 0; ks < 2; ++ks) {
      short8 af[4], bfr[4];
#pragma unroll
      for (int i = 0; i < 4; ++i) {
        af[i] = *(const short8*)((const char*)a_sm + oA[ks][i]);
        bfr[i] = *(const short8*)((const char*)b_sm + oB[ks][i]);
      }
#pragma unroll
      for (int i = 0; i < 4; ++i)
#pragma unroll
        for (int j = 0; j < 4; ++j)
          acc[i][j] = __builtin_amdgcn_mfma_f32_16x16x32_bf16(af[i], bfr[j], acc[i][j], 0, 0, 0);
    }
    __syncthreads();
  }
  // epilogue: C row = (lane>>4)*4 + reg, col = lane&15 (verified m89/m91 layout)
#pragma unroll
  for (int i = 0; i < 4; ++i) {
    int row = m0 + wr * 64 + i * 16 + lane_g * 4;
#pragma unroll
    for (int j = 0; j < 4; ++j) {
      int col = n0 + wc * 64 + j * 16 + lane_r;
#pragma unroll
      for (int r = 0; r < 4; ++r) {
        float v = acc[i][j][r];
        if (OUTF)
          ((float*)Cp)[(size_t)(row + r) * N + col] = v;
        else
          ((unsigned short*)Cp)[(size_t)(row + r) * N + col] = f2bf(v);
      }
    }
  }
}

// ---------------- fused RMSNorm + RoPE (+qg, + score-scale fold for q) ------
// one wave per (token, head) row of 128; q heads 0..15, k heads 16..19 (v untouched)
__global__ __launch_bounds__(256) void normrope_kernel(unsigned short* __restrict__ qkv,
                                                       const float* __restrict__ cost,
                                                       const float* __restrict__ sint,
                                                       const float* __restrict__ qg) {
  const int tid = threadIdx.x, l = tid & 63, w = tid >> 6;
  int row = blockIdx.x * 4 + w;          // 0 .. 81919
  int tok = row / 20, hh = row - tok * 20;
  int t = tok & 2047;
  bool isq = hh < 16;
  int col0 = isq ? hh * 128 : 2048 + (hh - 16) * 128;
  unsigned short* p = qkv + (size_t)tok * 3072 + col0 + 2 * l;
  unsigned int u = *(const unsigned int*)p;
  float x0 = bf2f((unsigned short)(u & 0xffffu));
  float x1 = bf2f((unsigned short)(u >> 16));
  float ss = x0 * x0 + x1 * x1;
#pragma unroll
  for (int m = 1; m < 64; m <<= 1) ss += __shfl_xor(ss, m);
  float rn = rsqrtf(ss * (1.0f / 128.0f) + 1.1920928955078125e-07f);
  float n0 = x0 * rn, n1 = x1 * rn;
  float p0 = __shfl_xor(n0, 32);   // partner half value
  float p1 = __shfl_xor(n1, 32);
  int jj = (2 * l) & 63;           // index within half
  float c0 = cost[t * 64 + jj], c1 = cost[t * 64 + jj + 1];
  float s0 = sint[t * 64 + jj], s1 = sint[t * 64 + jj + 1];
  float o0, o1;
  if (l < 32) { o0 = n0 * c0 + p0 * s0; o1 = n1 * c1 + p1 * s1; }
  else        { o0 = -p0 * s0 + n0 * c0; o1 = -p1 * s1 + n1 * c1; }
  if (isq) { float g = qg[hh] * 0.08838834764831845f; o0 *= g; o1 *= g; }  // fold 1/sqrt(128)
  *(unsigned int*)p = (unsigned)f2bf(o0) | ((unsigned)f2bf(o1) << 16);
}

// ---------------- flash attention: 64 q-rows/block, 4 waves x 16 rows, KVBLK=32 ----
__global__ __launch_bounds__(256) void attn_fa(const unsigned short* __restrict__ qkv,
                                               unsigned short* __restrict__ y) {
  extern __shared__ unsigned short sm[];
  unsigned short* q_sm = sm;               // [64][128] swizzled       16KB
  unsigned short* k_sm = q_sm + 64 * 128;  // [32][128] swizzled        8KB
  unsigned short* v_sm = k_sm + 32 * 128;  // [32][128] swizzled        8KB
  unsigned short* vt_sm = v_sm + 32 * 128; // [128][40] V^T, padded    10KB
  unsigned short* p_sm = vt_sm + 128 * 40; // 4 x [16][40]              5KB

  const int tid = threadIdx.x, l = tid & 63, w = tid >> 6;
  const int lane_r = l & 15, lane_g = l >> 4;
  const int qb = blockIdx.x, h = blockIdx.y, b = blockIdx.z;
  const int kvh = h >> 2;
  const int q0 = qb * 64;
  const size_t rowbase = (size_t)b * 2048;

  // ---- stage Q (1024 chunks, swizzled source) ----
#pragma unroll
  for (int t = 0; t < 4; ++t) {
    int idx = t * 256 + tid;
    int row = idx >> 4, c = idx & 15;
    int gc = c ^ (row & 7);
    GLOAD16(qkv + ((rowbase + q0 + row) * 3072 + h * 128 + gc * 8), &q_sm[idx * 8]);
  }

  // staging descriptors for K/V (512 chunks each)
  size_t kOff[2], vOff[2]; unsigned short* lK[2]; unsigned short* lV[2];
#pragma unroll
  for (int t = 0; t < 2; ++t) {
    int idx = t * 256 + tid;
    int row = idx >> 4, c = idx & 15;
    int gc = c ^ (row & 7);
    kOff[t] = (size_t)row * 3072 + 2048 + kvh * 128 + gc * 8;
    vOff[t] = (size_t)row * 3072 + 2560 + kvh * 128 + gc * 8;
    lK[t] = &k_sm[idx * 8];
    lV[t] = &v_sm[idx * 8];
  }
  // transpose descriptors (2 chunks of 8 per thread)
  int tr_d[2], tr_jc[2];
#pragma unroll
  for (int i = 0; i < 2; ++i) {
    int idx = i * 256 + tid;
    tr_d[i] = idx >> 2; tr_jc[i] = idx & 3;
  }
  // frag read offsets
  int oK[2][4];
#pragma unroll
  for (int ct = 0; ct < 2; ++ct)
#pragma unroll
    for (int ks = 0; ks < 4; ++ks) {
      int rk = ct * 16 + lane_r;
      oK[ct][ks] = ((rk * 128 + ks * 32 + lane_g * 8) * 2) ^ ((rk & 7) << 4);
    }
  int oV[8];
#pragma unroll
  for (int dt = 0; dt < 8; ++dt) oV[dt] = (dt * 16 + lane_r) * 80 + lane_g * 16;
  unsigned short* pw = p_sm + w * 16 * 40;
  const int oP = lane_r * 80 + lane_g * 16;

  f32x4 acc_o[8];
#pragma unroll
  for (int dt = 0; dt < 8; ++dt) acc_o[dt] = {0.f, 0.f, 0.f, 0.f};
  float mrun[4], lrun[4];
#pragma unroll
  for (int r = 0; r < 4; ++r) { mrun[r] = -1e30f; lrun[r] = 0.f; }

  short8 qf[4];
  const unsigned short* kvbase = qkv + rowbase * 3072;
  const int nkb = 2 * qb + 2;
  for (int kb = 0; kb < nkb; ++kb) {
    const int j0 = kb * 32;
    const unsigned short* src = kvbase + (size_t)j0 * 3072;
#pragma unroll
    for (int t = 0; t < 2; ++t) {
      GLOAD16(src + kOff[t], lK[t]);
      GLOAD16(src + vOff[t], lV[t]);
    }
    __syncthreads();  // B1: Q (first iter), K, V resident
    if (kb == 0) {
      int row = w * 16 + lane_r;
#pragma unroll
      for (int ks = 0; ks < 4; ++ks) {
        int off = ((row * 128 + ks * 32 + lane_g * 8) * 2) ^ ((row & 7) << 4);
        qf[ks] = *(const short8*)((const char*)q_sm + off);
      }
    }
    // ---- transpose V -> vt (padded stride 40) ----
#pragma unroll
    for (int i = 0; i < 2; ++i) {
      int d = tr_d[i], jc = tr_jc[i];
      short8 pk;
#pragma unroll
      for (int jjv = 0; jjv < 8; ++jjv) {
        int off = ((jc * 8 + jjv) * 256 + 2 * d) ^ (jjv << 4);
        pk[jjv] = *(const short*)((const char*)v_sm + off);
      }
      *(short8*)((char*)vt_sm + d * 80 + jc * 16) = pk;
    }
    // ---- S = Q @ K^T (scale pre-folded into q) ----
    f32x4 s[2];
    s[0] = {0.f, 0.f, 0.f, 0.f}; s[1] = {0.f, 0.f, 0.f, 0.f};
#pragma unroll
    for (int ct = 0; ct < 2; ++ct)
#pragma unroll
      for (int ks = 0; ks < 4; ++ks) {
        short8 kf = *(const short8*)((const char*)k_sm + oK[ct][ks]);
        s[ct] = __builtin_amdgcn_mfma_f32_16x16x32_bf16(qf[ks], kf, s[ct], 0, 0, 0);
      }
    // ---- causal mask ----
    if (j0 + 31 > q0 + w * 16) {
#pragma unroll
      for (int ct = 0; ct < 2; ++ct) {
        int jg = j0 + ct * 16 + lane_r;
#pragma unroll
        for (int r = 0; r < 4; ++r) {
          int ig = q0 + w * 16 + lane_g * 4 + r;
          if (jg > ig) s[ct][r] = -1e30f;
        }
      }
    }
    // ---- online softmax (rows owned per reg; 16-lane groups share a row) ----
    float corr[4];
#pragma unroll
    for (int r = 0; r < 4; ++r) {
      float mx = fmaxf(s[0][r], s[1][r]);
      mx = fmaxf(mx, __shfl_xor(mx, 1));
      mx = fmaxf(mx, __shfl_xor(mx, 2));
      mx = fmaxf(mx, __shfl_xor(mx, 4));
      mx = fmaxf(mx, __shfl_xor(mx, 8));
      float mn = fmaxf(mrun[r], mx);
      corr[r] = __expf(mrun[r] - mn);
      mrun[r] = mn;
      float e0 = __expf(s[0][r] - mn);
      float e1 = __expf(s[1][r] - mn);
      s[0][r] = e0; s[1][r] = e1;
      float rs = e0 + e1;
      rs += __shfl_xor(rs, 1); rs += __shfl_xor(rs, 2);
      rs += __shfl_xor(rs, 4); rs += __shfl_xor(rs, 8);
      lrun[r] = lrun[r] * corr[r] + rs;
    }
    // P -> LDS (wave-private)
#pragma unroll
    for (int ct = 0; ct < 2; ++ct)
#pragma unroll
      for (int r = 0; r < 4; ++r)
        pw[(lane_g * 4 + r) * 40 + ct * 16 + lane_r] = f2bf(s[ct][r]);
    // rescale O
#pragma unroll
    for (int dt = 0; dt < 8; ++dt)
#pragma unroll
      for (int r = 0; r < 4; ++r) acc_o[dt][r] *= corr[r];
    __syncthreads();  // B2: vt complete, all K/V reads done
    // ---- O += P @ V ----
    short8 pf = *(const short8*)((const char*)pw + oP);
#pragma unroll
    for (int dt = 0; dt < 8; ++dt) {
      short8 vf = *(const short8*)((const char*)vt_sm + oV[dt]);
      acc_o[dt] = __builtin_amdgcn_mfma_f32_16x16x32_bf16(pf, vf, acc_o[dt], 0, 0, 0);
    }
  }
  // ---- epilogue ----
  float inv[4];
#pragma unroll
  for (int r = 0; r < 4; ++r) inv[r] = 1.0f / lrun[r];
#pragma unroll
  for (int dt = 0; dt < 8; ++dt)
#pragma unroll
    for (int r = 0; r < 4; ++r) {
      size_t orow = rowbase + q0 + w * 16 + lane_g * 4 + r;
      y[orow * 2048 + h * 128 + dt * 16 + lane_r] = f2bf(acc_o[dt][r] * inv[r]);
    }
}

// ---------------- launch ----------------
extern "C" void kernel_launch(void* const* d_in, const int* in_sizes, int n_in,
                              void* d_out, int out_size, void* d_ws, size_t ws_size,
                              hipStream_t stream) {
  (void)in_sizes; (void)n_in; (void)out_size; (void)ws_size;
  const float* x  = (const float*)d_in[0];
  const float* qw = (const float*)d_in[1];
  const float* kw = (const float*)d_in[2];
  const float* vw = (const float*)d_in[3];
  const float* ow = (const float*)d_in[4];
  const float* qg = (const float*)d_in[5];

  char* ws = (char*)d_ws;
  unsigned short* xb   = (unsigned short*)(ws + 0);          // 16,777,216 B
  unsigned short* wqkv = (unsigned short*)(ws + 16777216);   // 12,582,912 B
  unsigned short* owb  = (unsigned short*)(ws + 29360128);   //  8,388,608 B
  unsigned short* qkvb = (unsigned short*)(ws + 37748736);   // 25,165,824 B
  unsigned short* y    = (unsigned short*)(ws + 62914560);   // 16,777,216 B
  float* cost          = (float*)(ws + 79691776);            //    524,288 B
  float* sint          = (float*)(ws + 80216064);            //    524,288 B  (end 80,740,352)

  prep_kernel<<<18944, 256, 0, stream>>>(x, qw, kw, vw, ow, xb, wqkv, owb, cost, sint);
  gemm_bt<0><<<dim3(3072 / 128, 4096 / 128), 256, 0, stream>>>(xb, wqkv, qkvb, 4096, 3072, 2048);
  normrope_kernel<<<20480, 256, 0, stream>>>(qkvb, cost, sint, qg);
  attn_fa<<<dim3(32, 16, 2), 256, 48128, stream>>>(qkvb, y);
  gemm_bt<1><<<dim3(2048 / 128, 4096 / 128), 256, 0, stream>>>(y, owb, d_out, 4096, 2048, 2048);
}

// Round 3
// 255.283 us; speedup vs baseline: 1.7349x; 1.7349x over previous
//
#include <hip/hip_runtime.h>
#include <hip/hip_bf16.h>
#include <stdint.h>

// B=2, T=2048, D=2048, NH=16, NKV=4, HD=128.  qkv width = 3072 (q 0..2047, k 2048..2559, v 2560..3071)

typedef __attribute__((ext_vector_type(8))) short short8;
typedef __attribute__((ext_vector_type(4))) float f32x4;

#define GLOAD16(gp, lp) \
  __builtin_amdgcn_global_load_lds((const __attribute__((address_space(1))) void*)(gp), \
                                   (__attribute__((address_space(3))) void*)(lp), 16, 0, 0)

__device__ __forceinline__ float bf2f(unsigned short u) {
  union { unsigned int i; float f; } v; v.i = ((unsigned int)u) << 16; return v.f;
}
__device__ __forceinline__ unsigned short f2bf(float f) {
  union { float fl; unsigned int i; } v; v.fl = f;
  unsigned int r = v.i + 0x7fffu + ((v.i >> 16) & 1u);
  return (unsigned short)(r >> 16);
}

// ---------------- prep: f32->bf16 conversions + rope tables ----------------
__global__ __launch_bounds__(256) void prep_kernel(
    const float* __restrict__ x, const float* __restrict__ qw,
    const float* __restrict__ kw, const float* __restrict__ vw,
    const float* __restrict__ ow,
    unsigned short* __restrict__ xb, unsigned short* __restrict__ wqkv,
    unsigned short* __restrict__ owb, float* __restrict__ cost, float* __restrict__ sint) {
  const int NX = 2097152;   // x elems/4
  const int NW = 1572864;   // wqkv elems/4
  const int NO = 1048576;   // ow elems/4
  const int NT = 131072;    // table entries (2048*64)
  int tid = blockIdx.x * 256 + threadIdx.x;
  if (tid < NX) {
    float4 v = ((const float4*)x)[tid];
    uint2 o; o.x = (unsigned)f2bf(v.x) | ((unsigned)f2bf(v.y) << 16);
    o.y = (unsigned)f2bf(v.z) | ((unsigned)f2bf(v.w) << 16);
    ((uint2*)xb)[tid] = o;
  } else if (tid < NX + NW) {
    int i = tid - NX; int e = i * 4;
    const float* src = (e < 4194304) ? (qw + e)
                     : (e < 5242880) ? (kw + (e - 4194304))
                                     : (vw + (e - 5242880));
    float4 v = *(const float4*)src;
    uint2 o; o.x = (unsigned)f2bf(v.x) | ((unsigned)f2bf(v.y) << 16);
    o.y = (unsigned)f2bf(v.z) | ((unsigned)f2bf(v.w) << 16);
    ((uint2*)wqkv)[i] = o;
  } else if (tid < NX + NW + NO) {
    int i = tid - NX - NW;
    float4 v = ((const float4*)ow)[i];
    uint2 o; o.x = (unsigned)f2bf(v.x) | ((unsigned)f2bf(v.y) << 16);
    o.y = (unsigned)f2bf(v.z) | ((unsigned)f2bf(v.w) << 16);
    ((uint2*)owb)[i] = o;
  } else if (tid < NX + NW + NO + NT) {
    int i = tid - NX - NW - NO;
    int t = i >> 6, j = i & 63;
    // T(2048) > TSL(1024) branch: inv = 1/(10000 * 2^((128/126)^(j/64)))
    float e = exp2f(0.02272008f * (float)j * (1.0f / 64.0f));   // (128/126)^(j/64)
    float inv = 1.0f / (10000.0f * exp2f(e));
    float f = (float)t * inv;
    cost[i] = cosf(f);
    sint[i] = sinf(f);
  }
}

// ---------------- GEMM C = A @ Bw^T   (A[M][K], Bw[N][K], bf16 in, bf16/f32 out) ----
template <int OUTF>  // 0 = bf16 out, 1 = f32 out
__global__ __launch_bounds__(256) void gemm_bt(const unsigned short* __restrict__ A,
                                               const unsigned short* __restrict__ Bw,
                                               void* __restrict__ Cp,
                                               int M, int N, int K) {
  __shared__ unsigned short a_sm[128 * 64];
  __shared__ unsigned short b_sm[128 * 64];
  const int tid = threadIdx.x;
  const int l = tid & 63, w = tid >> 6;
  const int lane_r = l & 15, lane_g = l >> 4;
  const int wr = w >> 1, wc = w & 1;
  const int m0 = blockIdx.y * 128, n0 = blockIdx.x * 128;

  f32x4 acc[4][4];
#pragma unroll
  for (int i = 0; i < 4; ++i)
#pragma unroll
    for (int j = 0; j < 4; ++j) acc[i][j] = {0.f, 0.f, 0.f, 0.f};

  const unsigned short* gA[4]; const unsigned short* gB[4];
  unsigned short* lA[4]; unsigned short* lB[4];
#pragma unroll
  for (int t = 0; t < 4; ++t) {
    int idx = t * 256 + tid;
    int row = idx >> 3, c = idx & 7;
    int gc = c ^ (row & 7);               // inverse-swizzled global source
    gA[t] = A + (size_t)(m0 + row) * K + gc * 8;
    gB[t] = Bw + (size_t)(n0 + row) * K + gc * 8;
    lA[t] = &a_sm[idx * 8];
    lB[t] = &b_sm[idx * 8];
  }
  int oA[2][4], oB[2][4];
#pragma unroll
  for (int ks = 0; ks < 2; ++ks)
#pragma unroll
    for (int i = 0; i < 4; ++i) {
      int ra = wr * 64 + i * 16 + lane_r;
      oA[ks][i] = ((ra * 64 + ks * 32 + lane_g * 8) * 2) ^ ((ra & 7) << 4);
      int rb = wc * 64 + i * 16 + lane_r;
      oB[ks][i] = ((rb * 64 + ks * 32 + lane_g * 8) * 2) ^ ((rb & 7) << 4);
    }

  for (int kt = 0; kt < K; kt += 64) {
#pragma unroll
    for (int t = 0; t < 4; ++t) {
      GLOAD16(gA[t] + kt, lA[t]);
      GLOAD16(gB[t] + kt, lB[t]);
    }
    __syncthreads();
#pragma unroll
    for (int ks = 0; ks < 2; ++ks) {
      short8 af[4], bfr[4];
#pragma unroll
      for (int i = 0; i < 4; ++i) {
        af[i] = *(const short8*)((const char*)a_sm + oA[ks][i]);
        bfr[i] = *(const short8*)((const char*)b_sm + oB[ks][i]);
      }
#pragma unroll
      for (int i = 0; i < 4; ++i)
#pragma unroll
        for (int j = 0; j < 4; ++j)
          acc[i][j] = __builtin_amdgcn_mfma_f32_16x16x32_bf16(af[i], bfr[j], acc[i][j], 0, 0, 0);
    }
    __syncthreads();
  }
#pragma unroll
  for (int i = 0; i < 4; ++i) {
    int row = m0 + wr * 64 + i * 16 + lane_g * 4;
#pragma unroll
    for (int j = 0; j < 4; ++j) {
      int col = n0 + wc * 64 + j * 16 + lane_r;
#pragma unroll
      for (int r = 0; r < 4; ++r) {
        float v = acc[i][j][r];
        if (OUTF)
          ((float*)Cp)[(size_t)(row + r) * N + col] = v;
        else
          ((unsigned short*)Cp)[(size_t)(row + r) * N + col] = f2bf(v);
      }
    }
  }
}

// ---------------- fused RMSNorm + RoPE (+qg, + score-scale fold for q) ------
__global__ __launch_bounds__(256) void normrope_kernel(unsigned short* __restrict__ qkv,
                                                       const float* __restrict__ cost,
                                                       const float* __restrict__ sint,
                                                       const float* __restrict__ qg) {
  const int tid = threadIdx.x, l = tid & 63, w = tid >> 6;
  int row = blockIdx.x * 4 + w;          // 0 .. 81919
  int tok = row / 20, hh = row - tok * 20;
  int t = tok & 2047;
  bool isq = hh < 16;
  int col0 = isq ? hh * 128 : 2048 + (hh - 16) * 128;
  unsigned short* p = qkv + (size_t)tok * 3072 + col0 + 2 * l;
  unsigned int u = *(const unsigned int*)p;
  float x0 = bf2f((unsigned short)(u & 0xffffu));
  float x1 = bf2f((unsigned short)(u >> 16));
  float ss = x0 * x0 + x1 * x1;
#pragma unroll
  for (int m = 1; m < 64; m <<= 1) ss += __shfl_xor(ss, m);
  float rn = rsqrtf(ss * (1.0f / 128.0f) + 1.1920928955078125e-07f);
  float n0 = x0 * rn, n1 = x1 * rn;
  float p0 = __shfl_xor(n0, 32);
  float p1 = __shfl_xor(n1, 32);
  int jj = (2 * l) & 63;
  float c0 = cost[t * 64 + jj], c1 = cost[t * 64 + jj + 1];
  float s0 = sint[t * 64 + jj], s1 = sint[t * 64 + jj + 1];
  float o0, o1;
  if (l < 32) { o0 = n0 * c0 + p0 * s0; o1 = n1 * c1 + p1 * s1; }
  else        { o0 = -p0 * s0 + n0 * c0; o1 = -p1 * s1 + n1 * c1; }
  if (isq) { float g = qg[hh] * 0.08838834764831845f; o0 *= g; o1 *= g; }
  *(unsigned int*)p = (unsigned)f2bf(o0) | ((unsigned)f2bf(o1) << 16);
}

// ---------------- flash attention v3 --------------------------------------
// 256 blocks (1/CU), 8 waves x 16 q-rows = 128 q-rows per Q-tile; each block does the
// complementary pair of Q-tiles (15-pi, pi) -> constant 34 KV-tiles per block.
// KVBLK=64; K,V double-buffered row-major swizzled; V transposed in-LDS (R1-verified
// method) into XOR-swizzled vt[128][64]; PV B-frags = contiguous short8 from vt.
// LDS: K dbuf 2x16K @0, V dbuf 2x16K @32768, vt 16K @65536, P 8x2K @81920 = 96KB.
__global__ __launch_bounds__(512) void attn_fa3(const unsigned short* __restrict__ qkv,
                                                unsigned short* __restrict__ y) {
  extern __shared__ char smc[];
  const int tid = threadIdx.x;
  const int l = tid & 63, w = tid >> 6;
  const int lane_r = l & 15, lane_g = l >> 4;

  int n = blockIdx.x;
  int pan = n & 7;            // panel -> XCD (blockIdx%8 heuristic)
  int b = pan >> 2, kvh = pan & 3;
  int idx2 = n >> 3;
  int h = kvh * 4 + (idx2 & 3);
  int pairIdx = idx2 >> 2;    // 0..7
  const size_t rowbase = (size_t)b * 2048;
  const unsigned short* kv = qkv + rowbase * 3072;

  // per-thread staging descriptors (2 chunks each for K and V; both row-major swizzled)
  int kg[2], vg[2], kl[2];
#pragma unroll
  for (int t = 0; t < 2; ++t) {
    int idx = t * 512 + tid;
    int row = idx >> 4, c = idx & 15, gc = c ^ (row & 7);
    kg[t] = row * 3072 + 2048 + kvh * 128 + gc * 8;
    vg[t] = row * 3072 + 2560 + kvh * 128 + gc * 8;
    kl[t] = idx * 16;
  }
  // V-transpose descriptors: thread handles (d, jb): reads rows j=jb*8..+8 at col d
  int trd[2], trjb[2];
#pragma unroll
  for (int t = 0; t < 2; ++t) {
    int idx = t * 512 + tid;
    trd[t] = idx & 127;
    trjb[t] = idx >> 7;
  }
  // K fragment byte offsets (buffer 0)
  int oK[4][4];
#pragma unroll
  for (int ct = 0; ct < 4; ++ct)
#pragma unroll
    for (int ks = 0; ks < 4; ++ks) {
      int rk = ct * 16 + lane_r;
      oK[ct][ks] = ((rk * 128 + ks * 32 + lane_g * 8) * 2) ^ ((rk & 7) << 4);
    }
  // vt fragment byte offsets: B-frag (kk, dt): row d = dt*16+lane_r, elems kk*32+lane_g*8..+8
  int oV[2][8];
#pragma unroll
  for (int kk = 0; kk < 2; ++kk)
#pragma unroll
    for (int dt = 0; dt < 8; ++dt) {
      int d = dt * 16 + lane_r;
      oV[kk][dt] = 65536 + ((d * 128 + kk * 64 + lane_g * 16) ^ ((d & 7) << 4));
    }
  // P offsets (wave-private, swizzled [16][64])
  const int pbase = 81920 + w * 2048;
  int pRow[4], pSw[4];
#pragma unroll
  for (int r = 0; r < 4; ++r) {
    int prow = lane_g * 4 + r;
    pRow[r] = prow * 128;
    pSw[r] = (prow & 7) << 4;
  }
  int oPr[2];
#pragma unroll
  for (int ks = 0; ks < 2; ++ks)
    oPr[ks] = pbase + ((lane_r * 128 + ks * 64 + lane_g * 16) ^ ((lane_r & 7) << 4));

  auto STAGE = [&](int tile, int bufsel) {
    const unsigned short* src = kv + (size_t)tile * 64 * 3072;
    char* kd = smc + bufsel * 16384;
    char* vd = smc + 32768 + bufsel * 16384;
#pragma unroll
    for (int t = 0; t < 2; ++t) {
      GLOAD16(src + kg[t], kd + kl[t]);
      GLOAD16(src + vg[t], vd + kl[t]);
    }
  };

#pragma unroll 1
  for (int phase = 0; phase < 2; ++phase) {
    const int qt = phase ? pairIdx : 15 - pairIdx;  // long tile first
    const int q0 = qt * 128;
    const int nkb = 2 * qt + 2;
    const int wrow0 = q0 + w * 16;

    STAGE(0, 0);
    // Q fragments in registers
    short8 qf[4];
#pragma unroll
    for (int ks = 0; ks < 4; ++ks)
      qf[ks] = *(const short8*)(qkv + (rowbase + wrow0 + lane_r) * 3072 + h * 128 + ks * 32 + lane_g * 8);

    f32x4 acc[8];
#pragma unroll
    for (int dt = 0; dt < 8; ++dt) acc[dt] = {0.f, 0.f, 0.f, 0.f};
    float mrun[4], lrun[4];
#pragma unroll
    for (int r = 0; r < 4; ++r) { mrun[r] = -1e30f; lrun[r] = 0.f; }

    __syncthreads();   // tile 0 resident

#pragma unroll 1
    for (int kb = 0; kb < nkb; ++kb) {
      const int cur = kb & 1;
      if (kb + 1 < nkb) STAGE(kb + 1, cur ^ 1);   // prefetch overlaps compute below
      const int j0 = kb * 64;
      const bool active = (j0 <= wrow0 + 15);
      // ---- cooperative V transpose: v_sm[cur] (swizzled [64][128]) -> vt[128][64] swz ----
      {
        const int vbase = 32768 + cur * 16384;
#pragma unroll
        for (int t = 0; t < 2; ++t) {
          int d = trd[t], jb = trjb[t];
          short8 pk;
#pragma unroll
          for (int jj = 0; jj < 8; ++jj) {
            int off = vbase + (((jb * 8 + jj) * 256 + 2 * d) ^ (jj << 4));
            pk[jj] = *(const short*)(smc + off);
          }
          *(short8*)(smc + 65536 + ((d * 128 + jb * 16) ^ ((d & 7) << 4))) = pk;
        }
      }
      f32x4 s[4];
      float corr[4];
      if (active) {
        const int kbb = cur * 16384;
        // ---- S = Q @ K^T ----
#pragma unroll
        for (int ct = 0; ct < 4; ++ct) s[ct] = {0.f, 0.f, 0.f, 0.f};
#pragma unroll
        for (int ct = 0; ct < 4; ++ct)
#pragma unroll
          for (int ks = 0; ks < 4; ++ks) {
            short8 kf = *(const short8*)(smc + kbb + oK[ct][ks]);
            s[ct] = __builtin_amdgcn_mfma_f32_16x16x32_bf16(qf[ks], kf, s[ct], 0, 0, 0);
          }
        // ---- causal mask ----
        if (j0 + 63 > wrow0) {
#pragma unroll
          for (int ct = 0; ct < 4; ++ct) {
            int jg = j0 + ct * 16 + lane_r;
#pragma unroll
            for (int r = 0; r < 4; ++r) {
              int ig = wrow0 + lane_g * 4 + r;
              if (jg > ig) s[ct][r] = -1e30f;
            }
          }
        }
        // ---- online softmax ----
#pragma unroll
        for (int r = 0; r < 4; ++r) {
          float mx = fmaxf(fmaxf(s[0][r], s[1][r]), fmaxf(s[2][r], s[3][r]));
          mx = fmaxf(mx, __shfl_xor(mx, 1));
          mx = fmaxf(mx, __shfl_xor(mx, 2));
          mx = fmaxf(mx, __shfl_xor(mx, 4));
          mx = fmaxf(mx, __shfl_xor(mx, 8));
          float mn = fmaxf(mrun[r], mx);
          corr[r] = __expf(mrun[r] - mn);
          mrun[r] = mn;
          float rs = 0.f;
#pragma unroll
          for (int ct = 0; ct < 4; ++ct) {
            float e = __expf(s[ct][r] - mn);
            s[ct][r] = e; rs += e;
          }
          rs += __shfl_xor(rs, 1); rs += __shfl_xor(rs, 2);
          rs += __shfl_xor(rs, 4); rs += __shfl_xor(rs, 8);
          lrun[r] = lrun[r] * corr[r] + rs;
        }
        // ---- P -> LDS (wave-private, swizzled) ----
#pragma unroll
        for (int ct = 0; ct < 4; ++ct) {
          int cb = (ct * 16 + lane_r) * 2;
#pragma unroll
          for (int r = 0; r < 4; ++r)
            *(unsigned short*)(smc + pbase + ((pRow[r] + cb) ^ pSw[r])) = f2bf(s[ct][r]);
        }
        // ---- rescale O ----
#pragma unroll
        for (int dt = 0; dt < 8; ++dt)
#pragma unroll
          for (int r = 0; r < 4; ++r) acc[dt][r] *= corr[r];
      }
      __syncthreads();   // B_mid: vt + P complete
      if (active) {
        // ---- O += P @ V ----
        short8 pf[2];
        pf[0] = *(const short8*)(smc + oPr[0]);
        pf[1] = *(const short8*)(smc + oPr[1]);
#pragma unroll
        for (int kk = 0; kk < 2; ++kk)
#pragma unroll
          for (int dt = 0; dt < 8; ++dt) {
            short8 vf = *(const short8*)(smc + oV[kk][dt]);
            acc[dt] = __builtin_amdgcn_mfma_f32_16x16x32_bf16(pf[kk], vf, acc[dt], 0, 0, 0);
          }
      }
      __syncthreads();   // B_end: prefetch drained; vt/K/V safe to overwrite next iter
    }
    // ---- epilogue ----
    float inv[4];
#pragma unroll
    for (int r = 0; r < 4; ++r) inv[r] = 1.0f / lrun[r];
#pragma unroll
    for (int dt = 0; dt < 8; ++dt)
#pragma unroll
      for (int r = 0; r < 4; ++r) {
        size_t orow = rowbase + wrow0 + lane_g * 4 + r;
        y[orow * 2048 + h * 128 + dt * 16 + lane_r] = f2bf(acc[dt][r] * inv[r]);
      }
  }
}

// ---------------- launch ----------------
extern "C" void kernel_launch(void* const* d_in, const int* in_sizes, int n_in,
                              void* d_out, int out_size, void* d_ws, size_t ws_size,
                              hipStream_t stream) {
  (void)in_sizes; (void)n_in; (void)out_size; (void)ws_size;
  const float* x  = (const float*)d_in[0];
  const float* qw = (const float*)d_in[1];
  const float* kw = (const float*)d_in[2];
  const float* vw = (const float*)d_in[3];
  const float* ow = (const float*)d_in[4];
  const float* qg = (const float*)d_in[5];

  char* ws = (char*)d_ws;
  unsigned short* xb   = (unsigned short*)(ws + 0);
  unsigned short* wqkv = (unsigned short*)(ws + 16777216);
  unsigned short* owb  = (unsigned short*)(ws + 29360128);
  unsigned short* qkvb = (unsigned short*)(ws + 37748736);
  unsigned short* y    = (unsigned short*)(ws + 62914560);
  float* cost          = (float*)(ws + 79691776);
  float* sint          = (float*)(ws + 80216064);

  prep_kernel<<<18944, 256, 0, stream>>>(x, qw, kw, vw, ow, xb, wqkv, owb, cost, sint);
  gemm_bt<0><<<dim3(3072 / 128, 4096 / 128), 256, 0, stream>>>(xb, wqkv, qkvb, 4096, 3072, 2048);
  normrope_kernel<<<20480, 256, 0, stream>>>(qkvb, cost, sint, qg);
  attn_fa3<<<256, 512, 98304, stream>>>(qkvb, y);
  gemm_bt<1><<<dim3(2048 / 128, 4096 / 128), 256, 0, stream>>>(y, owb, d_out, 4096, 2048, 2048);
}

// Round 4
// 227.953 us; speedup vs baseline: 1.9429x; 1.1199x over previous
//
#include <hip/hip_runtime.h>
#include <hip/hip_bf16.h>
#include <stdint.h>

// B=2, T=2048, D=2048, NH=16, NKV=4, HD=128.  qkv width = 3072 (q 0..2047, k 2048..2559, v 2560..3071)

typedef __attribute__((ext_vector_type(8))) short short8;
typedef __attribute__((ext_vector_type(4))) float f32x4;

#define GLOAD16(gp, lp) \
  __builtin_amdgcn_global_load_lds((const __attribute__((address_space(1))) void*)(gp), \
                                   (__attribute__((address_space(3))) void*)(lp), 16, 0, 0)

__device__ __forceinline__ float bf2f(unsigned short u) {
  union { unsigned int i; float f; } v; v.i = ((unsigned int)u) << 16; return v.f;
}
__device__ __forceinline__ unsigned short f2bf(float f) {
  union { float fl; unsigned int i; } v; v.fl = f;
  unsigned int r = v.i + 0x7fffu + ((v.i >> 16) & 1u);
  return (unsigned short)(r >> 16);
}

// ---------------- prep: f32->bf16 conversions + rope tables ----------------
__global__ __launch_bounds__(256) void prep_kernel(
    const float* __restrict__ x, const float* __restrict__ qw,
    const float* __restrict__ kw, const float* __restrict__ vw,
    const float* __restrict__ ow,
    unsigned short* __restrict__ xb, unsigned short* __restrict__ wqkv,
    unsigned short* __restrict__ owb, float* __restrict__ cost, float* __restrict__ sint) {
  const int NX = 2097152;   // x elems/4
  const int NW = 1572864;   // wqkv elems/4
  const int NO = 1048576;   // ow elems/4
  const int NT = 131072;    // table entries (2048*64)
  int tid = blockIdx.x * 256 + threadIdx.x;
  if (tid < NX) {
    float4 v = ((const float4*)x)[tid];
    uint2 o; o.x = (unsigned)f2bf(v.x) | ((unsigned)f2bf(v.y) << 16);
    o.y = (unsigned)f2bf(v.z) | ((unsigned)f2bf(v.w) << 16);
    ((uint2*)xb)[tid] = o;
  } else if (tid < NX + NW) {
    int i = tid - NX; int e = i * 4;
    const float* src = (e < 4194304) ? (qw + e)
                     : (e < 5242880) ? (kw + (e - 4194304))
                                     : (vw + (e - 5242880));
    float4 v = *(const float4*)src;
    uint2 o; o.x = (unsigned)f2bf(v.x) | ((unsigned)f2bf(v.y) << 16);
    o.y = (unsigned)f2bf(v.z) | ((unsigned)f2bf(v.w) << 16);
    ((uint2*)wqkv)[i] = o;
  } else if (tid < NX + NW + NO) {
    int i = tid - NX - NW;
    float4 v = ((const float4*)ow)[i];
    uint2 o; o.x = (unsigned)f2bf(v.x) | ((unsigned)f2bf(v.y) << 16);
    o.y = (unsigned)f2bf(v.z) | ((unsigned)f2bf(v.w) << 16);
    ((uint2*)owb)[i] = o;
  } else if (tid < NX + NW + NO + NT) {
    int i = tid - NX - NW - NO;
    int t = i >> 6, j = i & 63;
    // T(2048) > TSL(1024) branch: inv = 1/(10000 * 2^((128/126)^(j/64)))
    float e = exp2f(0.02272008f * (float)j * (1.0f / 64.0f));   // (128/126)^(j/64)
    float inv = 1.0f / (10000.0f * exp2f(e));
    float f = (float)t * inv;
    cost[i] = cosf(f);
    sint[i] = sinf(f);
  }
}

// ---------------- GEMM C = A @ Bw^T   (A[M][K], Bw[N][K], bf16 in, bf16/f32 out) ----
template <int OUTF>  // 0 = bf16 out, 1 = f32 out
__global__ __launch_bounds__(256) void gemm_bt(const unsigned short* __restrict__ A,
                                               const unsigned short* __restrict__ Bw,
                                               void* __restrict__ Cp,
                                               int M, int N, int K) {
  __shared__ unsigned short a_sm[128 * 64];
  __shared__ unsigned short b_sm[128 * 64];
  const int tid = threadIdx.x;
  const int l = tid & 63, w = tid >> 6;
  const int lane_r = l & 15, lane_g = l >> 4;
  const int wr = w >> 1, wc = w & 1;
  const int m0 = blockIdx.y * 128, n0 = blockIdx.x * 128;

  f32x4 acc[4][4];
#pragma unroll
  for (int i = 0; i < 4; ++i)
#pragma unroll
    for (int j = 0; j < 4; ++j) acc[i][j] = {0.f, 0.f, 0.f, 0.f};

  const unsigned short* gA[4]; const unsigned short* gB[4];
  unsigned short* lA[4]; unsigned short* lB[4];
#pragma unroll
  for (int t = 0; t < 4; ++t) {
    int idx = t * 256 + tid;
    int row = idx >> 3, c = idx & 7;
    int gc = c ^ (row & 7);               // inverse-swizzled global source
    gA[t] = A + (size_t)(m0 + row) * K + gc * 8;
    gB[t] = Bw + (size_t)(n0 + row) * K + gc * 8;
    lA[t] = &a_sm[idx * 8];
    lB[t] = &b_sm[idx * 8];
  }
  int oA[2][4], oB[2][4];
#pragma unroll
  for (int ks = 0; ks < 2; ++ks)
#pragma unroll
    for (int i = 0; i < 4; ++i) {
      int ra = wr * 64 + i * 16 + lane_r;
      oA[ks][i] = ((ra * 64 + ks * 32 + lane_g * 8) * 2) ^ ((ra & 7) << 4);
      int rb = wc * 64 + i * 16 + lane_r;
      oB[ks][i] = ((rb * 64 + ks * 32 + lane_g * 8) * 2) ^ ((rb & 7) << 4);
    }

  for (int kt = 0; kt < K; kt += 64) {
#pragma unroll
    for (int t = 0; t < 4; ++t) {
      GLOAD16(gA[t] + kt, lA[t]);
      GLOAD16(gB[t] + kt, lB[t]);
    }
    __syncthreads();
#pragma unroll
    for (int ks = 0; ks < 2; ++ks) {
      short8 af[4], bfr[4];
#pragma unroll
      for (int i = 0; i < 4; ++i) {
        af[i] = *(const short8*)((const char*)a_sm + oA[ks][i]);
        bfr[i] = *(const short8*)((const char*)b_sm + oB[ks][i]);
      }
#pragma unroll
      for (int i = 0; i < 4; ++i)
#pragma unroll
        for (int j = 0; j < 4; ++j)
          acc[i][j] = __builtin_amdgcn_mfma_f32_16x16x32_bf16(af[i], bfr[j], acc[i][j], 0, 0, 0);
    }
    __syncthreads();
  }
#pragma unroll
  for (int i = 0; i < 4; ++i) {
    int row = m0 + wr * 64 + i * 16 + lane_g * 4;
#pragma unroll
    for (int j = 0; j < 4; ++j) {
      int col = n0 + wc * 64 + j * 16 + lane_r;
#pragma unroll
      for (int r = 0; r < 4; ++r) {
        float v = acc[i][j][r];
        if (OUTF)
          ((float*)Cp)[(size_t)(row + r) * N + col] = v;
        else
          ((unsigned short*)Cp)[(size_t)(row + r) * N + col] = f2bf(v);
      }
    }
  }
}

// ---------------- fused RMSNorm + RoPE (+qg, + score-scale fold for q) ------
__global__ __launch_bounds__(256) void normrope_kernel(unsigned short* __restrict__ qkv,
                                                       const float* __restrict__ cost,
                                                       const float* __restrict__ sint,
                                                       const float* __restrict__ qg) {
  const int tid = threadIdx.x, l = tid & 63, w = tid >> 6;
  int row = blockIdx.x * 4 + w;          // 0 .. 81919
  int tok = row / 20, hh = row - tok * 20;
  int t = tok & 2047;
  bool isq = hh < 16;
  int col0 = isq ? hh * 128 : 2048 + (hh - 16) * 128;
  unsigned short* p = qkv + (size_t)tok * 3072 + col0 + 2 * l;
  unsigned int u = *(const unsigned int*)p;
  float x0 = bf2f((unsigned short)(u & 0xffffu));
  float x1 = bf2f((unsigned short)(u >> 16));
  float ss = x0 * x0 + x1 * x1;
#pragma unroll
  for (int m = 1; m < 64; m <<= 1) ss += __shfl_xor(ss, m);
  float rn = rsqrtf(ss * (1.0f / 128.0f) + 1.1920928955078125e-07f);
  float n0 = x0 * rn, n1 = x1 * rn;
  float p0 = __shfl_xor(n0, 32);
  float p1 = __shfl_xor(n1, 32);
  int jj = (2 * l) & 63;
  float c0 = cost[t * 64 + jj], c1 = cost[t * 64 + jj + 1];
  float s0 = sint[t * 64 + jj], s1 = sint[t * 64 + jj + 1];
  float o0, o1;
  if (l < 32) { o0 = n0 * c0 + p0 * s0; o1 = n1 * c1 + p1 * s1; }
  else        { o0 = -p0 * s0 + n0 * c0; o1 = -p1 * s1 + n1 * c1; }
  if (isq) { float g = qg[hh] * 0.08838834764831845f; o0 *= g; o1 *= g; }
  *(unsigned int*)p = (unsigned)f2bf(o0) | ((unsigned)f2bf(o1) << 16);
}

// ---------------- V transpose: V[b][t][kvh][d] -> vtg[b*4+kvh][d][t] ----------
__global__ __launch_bounds__(256) void vtrans_kernel(const unsigned short* __restrict__ qkv,
                                                     unsigned short* __restrict__ vtg) {
  __shared__ unsigned short tile[64][132];   // [t][d], pad 4
  int bid = blockIdx.x;                      // 256 blocks
  int pan = bid & 7, tt = bid >> 3;          // pan = b*4+kvh, tt = t-tile
  int b = pan >> 2, kvh = pan & 3;
  int t0 = tt * 64;
  const unsigned short* src = qkv + ((size_t)(b * 2048 + t0)) * 3072 + 2560 + kvh * 128;
#pragma unroll
  for (int i = 0; i < 8; ++i) {
    int idx = i * 256 + threadIdx.x;         // 0..2047 uint2 loads
    int row = idx >> 5, c4 = idx & 31;
    uint2 v = *(const uint2*)(src + (size_t)row * 3072 + c4 * 4);
    *(uint2*)&tile[row][c4 * 4] = v;
  }
  __syncthreads();
  unsigned short* dst = vtg + (size_t)pan * 262144 + t0;
#pragma unroll
  for (int i = 0; i < 8; ++i) {
    int idx = i * 256 + threadIdx.x;
    int d = idx >> 4, tc = idx & 15;
    unsigned short a0 = tile[tc * 4 + 0][d], a1 = tile[tc * 4 + 1][d];
    unsigned short a2 = tile[tc * 4 + 2][d], a3 = tile[tc * 4 + 3][d];
    uint2 o; o.x = (unsigned)a0 | ((unsigned)a1 << 16);
    o.y = (unsigned)a2 | ((unsigned)a3 << 16);
    *(uint2*)(dst + (size_t)d * 2048 + tc * 4) = o;
  }
}

// ---------------- flash attention v4 --------------------------------------
// 256 blocks (1/CU), 8 waves x 16 q-rows = 128-row Q-tiles; complementary tile pairs.
// KVBLK=64. Swapped QK^T (S^T = mfma(K,Q)): softmax lane-local (2 shfl). V^T staged
// from global (no in-LDS transpose). P: 4 x ds_write_b64 + 2 x ds_read_b128, swizzled.
// One barrier per KV-tile. LDS: K dbuf 2x16K @0, V^T dbuf 2x16K @32768, P 8x2K @65536 = 80KB.
__global__ __launch_bounds__(512) void attn_fa4(const unsigned short* __restrict__ qkv,
                                                const unsigned short* __restrict__ vtg,
                                                unsigned short* __restrict__ y) {
  extern __shared__ char smc[];
  const int tid = threadIdx.x;
  const int l = tid & 63, w = tid >> 6;
  const int lane_r = l & 15, lane_g = l >> 4;

  int n = blockIdx.x;
  int pan = n & 7;            // panel -> XCD (blockIdx%8 heuristic)
  int b = pan >> 2, kvh = pan & 3;
  int idx2 = n >> 3;
  int h = kvh * 4 + (idx2 & 3);
  int pairIdx = idx2 >> 2;    // 0..7
  const size_t rowbase = (size_t)b * 2048;
  const unsigned short* kvK = qkv + rowbase * 3072;
  const unsigned short* vtp = vtg + (size_t)pan * 262144;

  // staging descriptors
  int kg[2], vg[2], sl[2];
#pragma unroll
  for (int t = 0; t < 2; ++t) {
    int idx = t * 512 + tid;
    { int row = idx >> 4, c = idx & 15, gc = c ^ (row & 7);
      kg[t] = row * 3072 + 2048 + kvh * 128 + gc * 8; }
    { int d = idx >> 3, c = idx & 7, gc = c ^ (d & 7);
      vg[t] = d * 2048 + gc * 8; }
    sl[t] = idx * 16;
  }
  const int swz = (lane_r & 7) << 4;
  // K frag offsets: row = ct*16+lane_r (row stride 256B)
  int oK[4][4];
#pragma unroll
  for (int ct = 0; ct < 4; ++ct)
#pragma unroll
    for (int ks = 0; ks < 4; ++ks)
      oK[ct][ks] = ((ct * 16 + lane_r) * 256 + ks * 64 + lane_g * 16) ^ swz;
  // V^T frag offsets: row d = dt*16+lane_r (row stride 128B), rel to vbase
  int oV[2][8];
#pragma unroll
  for (int kk = 0; kk < 2; ++kk)
#pragma unroll
    for (int dt = 0; dt < 8; ++dt)
      oV[kk][dt] = ((dt * 16 + lane_r) * 128 + kk * 64 + lane_g * 16) ^ swz;
  // P offsets (wave-private [16 q][64 k] bf16, swizzled)
  const int pbase = 65536 + w * 2048;
  int pw_off[4];
#pragma unroll
  for (int ct = 0; ct < 4; ++ct)
    pw_off[ct] = pbase + lane_r * 128 + ((ct * 32 + lane_g * 8) ^ swz);
  int pr_off[2];
#pragma unroll
  for (int kk = 0; kk < 2; ++kk)
    pr_off[kk] = pbase + lane_r * 128 + ((kk * 64 + lane_g * 16) ^ swz);

  auto STAGE = [&](int tile, int bufsel) {
    const unsigned short* srcK = kvK + (size_t)tile * 64 * 3072;
    const unsigned short* srcV = vtp + tile * 64;
    char* kd = smc + bufsel * 16384;
    char* vd = smc + 32768 + bufsel * 16384;
#pragma unroll
    for (int t = 0; t < 2; ++t) {
      GLOAD16(srcK + kg[t], kd + sl[t]);
      GLOAD16(srcV + vg[t], vd + sl[t]);
    }
  };

#pragma unroll 1
  for (int phase = 0; phase < 2; ++phase) {
    const int qt = phase ? pairIdx : 15 - pairIdx;  // long tile first
    const int q0 = qt * 128;
    const int nkb = 2 * qt + 2;
    const int wrow0 = q0 + w * 16;
    const int qrow = wrow0 + lane_r;    // this lane's q row (all regs)

    STAGE(0, 0);
    short8 qf[4];
#pragma unroll
    for (int ks = 0; ks < 4; ++ks)
      qf[ks] = *(const short8*)(qkv + (rowbase + qrow) * 3072 + h * 128 + ks * 32 + lane_g * 8);

    f32x4 acc[8];
#pragma unroll
    for (int dt = 0; dt < 8; ++dt) acc[dt] = {0.f, 0.f, 0.f, 0.f};
    float mrun = -1e30f, lrun = 0.f;

    __syncthreads();   // tile 0 resident

#pragma unroll 1
    for (int kb = 0; kb < nkb; ++kb) {
      const int cur = kb & 1;
      if (kb + 1 < nkb) STAGE(kb + 1, cur ^ 1);   // prefetch overlaps compute
      const int j0 = kb * 64;
      const bool active = (j0 <= wrow0 + 15);
      if (active) {
        const int kbb = cur * 16384;
        // ---- S^T = K @ Q^T : S^T[k=ct*16+lane_g*4+r][q=lane_r] ----
        f32x4 s[4];
#pragma unroll
        for (int ct = 0; ct < 4; ++ct) s[ct] = {0.f, 0.f, 0.f, 0.f};
        __builtin_amdgcn_s_setprio(1);
#pragma unroll
        for (int ct = 0; ct < 4; ++ct)
#pragma unroll
          for (int ks = 0; ks < 4; ++ks) {
            short8 kf = *(const short8*)(smc + kbb + oK[ct][ks]);
            s[ct] = __builtin_amdgcn_mfma_f32_16x16x32_bf16(kf, qf[ks], s[ct], 0, 0, 0);
          }
        __builtin_amdgcn_s_setprio(0);
        // ---- causal mask (k = j0+ct*16+lane_g*4+r, q = qrow) ----
        if (j0 + 63 > wrow0) {
#pragma unroll
          for (int ct = 0; ct < 4; ++ct) {
            int kg0 = j0 + ct * 16 + lane_g * 4;
#pragma unroll
            for (int r = 0; r < 4; ++r)
              if (kg0 + r > qrow) s[ct][r] = -1e30f;
          }
        }
        // ---- online softmax (lane-local row) ----
        float mx = s[0][0];
#pragma unroll
        for (int ct = 0; ct < 4; ++ct)
#pragma unroll
          for (int r = 0; r < 4; ++r) mx = fmaxf(mx, s[ct][r]);
        mx = fmaxf(mx, __shfl_xor(mx, 16));
        mx = fmaxf(mx, __shfl_xor(mx, 32));
        float mn = fmaxf(mrun, mx);
        float corr = __expf(mrun - mn);
        mrun = mn;
        float rs = 0.f;
#pragma unroll
        for (int ct = 0; ct < 4; ++ct)
#pragma unroll
          for (int r = 0; r < 4; ++r) {
            float e = __expf(s[ct][r] - mn);
            s[ct][r] = e; rs += e;
          }
        rs += __shfl_xor(rs, 16);
        rs += __shfl_xor(rs, 32);
        lrun = lrun * corr + rs;
        // ---- P write (packed b64, swizzled) ----
#pragma unroll
        for (int ct = 0; ct < 4; ++ct) {
          uint2 pv;
          pv.x = (unsigned)f2bf(s[ct][0]) | ((unsigned)f2bf(s[ct][1]) << 16);
          pv.y = (unsigned)f2bf(s[ct][2]) | ((unsigned)f2bf(s[ct][3]) << 16);
          *(uint2*)(smc + pw_off[ct]) = pv;
        }
        // ---- rescale O ----
#pragma unroll
        for (int dt = 0; dt < 8; ++dt)
#pragma unroll
          for (int r = 0; r < 4; ++r) acc[dt][r] *= corr;
        // ---- O^T += V^T @ P^T ----
        short8 pf[2];
        pf[0] = *(const short8*)(smc + pr_off[0]);
        pf[1] = *(const short8*)(smc + pr_off[1]);
        const int vbase = 32768 + cur * 16384;
        __builtin_amdgcn_s_setprio(1);
#pragma unroll
        for (int kk = 0; kk < 2; ++kk)
#pragma unroll
          for (int dt = 0; dt < 8; ++dt) {
            short8 vf = *(const short8*)(smc + vbase + oV[kk][dt]);
            acc[dt] = __builtin_amdgcn_mfma_f32_16x16x32_bf16(vf, pf[kk], acc[dt], 0, 0, 0);
          }
        __builtin_amdgcn_s_setprio(0);
      }
      __syncthreads();   // prefetch drained; all waves done with cur bufs
    }
    // ---- epilogue: O^T[d=dt*16+lane_g*4+r][q=lane_r], pack 4 d per store ----
    float linv = 1.0f / lrun;
    unsigned short* yrow = y + (rowbase + qrow) * 2048 + h * 128;
#pragma unroll
    for (int dt = 0; dt < 8; ++dt) {
      uint2 o;
      o.x = (unsigned)f2bf(acc[dt][0] * linv) | ((unsigned)f2bf(acc[dt][1] * linv) << 16);
      o.y = (unsigned)f2bf(acc[dt][2] * linv) | ((unsigned)f2bf(acc[dt][3] * linv) << 16);
      *(uint2*)(yrow + dt * 16 + lane_g * 4) = o;
    }
  }
}

// ---------------- launch ----------------
extern "C" void kernel_launch(void* const* d_in, const int* in_sizes, int n_in,
                              void* d_out, int out_size, void* d_ws, size_t ws_size,
                              hipStream_t stream) {
  (void)in_sizes; (void)n_in; (void)out_size; (void)ws_size;
  const float* x  = (const float*)d_in[0];
  const float* qw = (const float*)d_in[1];
  const float* kw = (const float*)d_in[2];
  const float* vw = (const float*)d_in[3];
  const float* ow = (const float*)d_in[4];
  const float* qg = (const float*)d_in[5];

  char* ws = (char*)d_ws;
  unsigned short* xb   = (unsigned short*)(ws + 0);          // dead after gemm1
  unsigned short* vtg  = (unsigned short*)(ws + 0);          // aliases xb (4 MB)
  unsigned short* wqkv = (unsigned short*)(ws + 16777216);
  unsigned short* owb  = (unsigned short*)(ws + 29360128);
  unsigned short* qkvb = (unsigned short*)(ws + 37748736);
  unsigned short* y    = (unsigned short*)(ws + 62914560);
  float* cost          = (float*)(ws + 79691776);
  float* sint          = (float*)(ws + 80216064);

  prep_kernel<<<18944, 256, 0, stream>>>(x, qw, kw, vw, ow, xb, wqkv, owb, cost, sint);
  gemm_bt<0><<<dim3(3072 / 128, 4096 / 128), 256, 0, stream>>>(xb, wqkv, qkvb, 4096, 3072, 2048);
  normrope_kernel<<<20480, 256, 0, stream>>>(qkvb, cost, sint, qg);
  vtrans_kernel<<<256, 256, 0, stream>>>(qkvb, vtg);
  attn_fa4<<<256, 512, 81920, stream>>>(qkvb, vtg, y);
  gemm_bt<1><<<dim3(2048 / 128, 4096 / 128), 256, 0, stream>>>(y, owb, d_out, 4096, 2048, 2048);
}

// Round 5
// 214.373 us; speedup vs baseline: 2.0660x; 1.0633x over previous
//
#include <hip/hip_runtime.h>
#include <hip/hip_bf16.h>
#include <stdint.h>

// B=2, T=2048, D=2048, NH=16, NKV=4, HD=128.  qkv width = 3072 (q 0..2047, k 2048..2559, v 2560..3071)

typedef __attribute__((ext_vector_type(8))) short short8;
typedef __attribute__((ext_vector_type(4))) float f32x4;

#define GLOAD16(gp, lp) \
  __builtin_amdgcn_global_load_lds((const __attribute__((address_space(1))) void*)(gp), \
                                   (__attribute__((address_space(3))) void*)(lp), 16, 0, 0)

__device__ __forceinline__ float bf2f(unsigned short u) {
  union { unsigned int i; float f; } v; v.i = ((unsigned int)u) << 16; return v.f;
}
__device__ __forceinline__ unsigned short f2bf(float f) {
  union { float fl; unsigned int i; } v; v.fl = f;
  unsigned int r = v.i + 0x7fffu + ((v.i >> 16) & 1u);
  return (unsigned short)(r >> 16);
}

// ---------------- prep: f32->bf16 conversions + rope tables ----------------
__global__ __launch_bounds__(256) void prep_kernel(
    const float* __restrict__ x, const float* __restrict__ qw,
    const float* __restrict__ kw, const float* __restrict__ vw,
    const float* __restrict__ ow,
    unsigned short* __restrict__ xb, unsigned short* __restrict__ wqkv,
    unsigned short* __restrict__ owb, float* __restrict__ cost, float* __restrict__ sint) {
  const int NX = 2097152;   // x elems/4
  const int NW = 1572864;   // wqkv elems/4
  const int NO = 1048576;   // ow elems/4
  const int NT = 131072;    // table entries (2048*64)
  int tid = blockIdx.x * 256 + threadIdx.x;
  if (tid < NX) {
    float4 v = ((const float4*)x)[tid];
    uint2 o; o.x = (unsigned)f2bf(v.x) | ((unsigned)f2bf(v.y) << 16);
    o.y = (unsigned)f2bf(v.z) | ((unsigned)f2bf(v.w) << 16);
    ((uint2*)xb)[tid] = o;
  } else if (tid < NX + NW) {
    int i = tid - NX; int e = i * 4;
    const float* src = (e < 4194304) ? (qw + e)
                     : (e < 5242880) ? (kw + (e - 4194304))
                                     : (vw + (e - 5242880));
    float4 v = *(const float4*)src;
    uint2 o; o.x = (unsigned)f2bf(v.x) | ((unsigned)f2bf(v.y) << 16);
    o.y = (unsigned)f2bf(v.z) | ((unsigned)f2bf(v.w) << 16);
    ((uint2*)wqkv)[i] = o;
  } else if (tid < NX + NW + NO) {
    int i = tid - NX - NW;
    float4 v = ((const float4*)ow)[i];
    uint2 o; o.x = (unsigned)f2bf(v.x) | ((unsigned)f2bf(v.y) << 16);
    o.y = (unsigned)f2bf(v.z) | ((unsigned)f2bf(v.w) << 16);
    ((uint2*)owb)[i] = o;
  } else if (tid < NX + NW + NO + NT) {
    int i = tid - NX - NW - NO;
    int t = i >> 6, j = i & 63;
    // T(2048) > TSL(1024) branch: inv = 1/(10000 * 2^((128/126)^(j/64)))
    float e = exp2f(0.02272008f * (float)j * (1.0f / 64.0f));   // (128/126)^(j/64)
    float inv = 1.0f / (10000.0f * exp2f(e));
    float f = (float)t * inv;
    cost[i] = cosf(f);
    sint[i] = sinf(f);
  }
}

// ---------------- GEMM v2: C = A @ Bw^T  (bf16 in, bf16/f32 out) ------------
// BM=256, BN=128, BK=64, 512 threads (8 waves 4Mx2N, wave-tile 64x64).
// 3-deep K-step LDS ring (3 x 48KB = 144KB); stage(s+2) each step; counted
// s_waitcnt vmcnt(6) + raw s_barrier (no drain) -> loads stay in flight (T3/T4).
template <int OUTF>  // 0 = bf16 out, 1 = f32 out
__global__ __launch_bounds__(512) void gemm_bt2(const unsigned short* __restrict__ A,
                                                const unsigned short* __restrict__ Bw,
                                                void* __restrict__ Cp,
                                                int MT, int NT, int N, int K) {
  extern __shared__ char smc[];   // buf q at q*49152: A 32KB, B 16KB
  const int tid = threadIdx.x;
  const int l = tid & 63, w = tid >> 6;
  const int lane_r = l & 15, lane_g = l >> 4;
  const int wr = w >> 1, wc = w & 1;

  // bijective XCD swizzle (nwg % 8 == 0 for both gemms)
  int nwg = MT * NT, qch = nwg >> 3;
  int orig = blockIdx.x;
  int wgid = (orig & 7) * qch + (orig >> 3);
  int by = wgid % MT;            // M tile (consecutive wgid per XCD share B panels)
  int bx = wgid / MT;            // N tile
  const int m0 = by * 256, n0 = bx * 128;

  f32x4 acc[4][4];
#pragma unroll
  for (int i = 0; i < 4; ++i)
#pragma unroll
    for (int j = 0; j < 4; ++j) acc[i][j] = {0.f, 0.f, 0.f, 0.f};

  // staging descriptors: A 2048 chunks (4/thread), B 1024 chunks (2/thread)
  const unsigned short* gA[4]; int lA[4];
#pragma unroll
  for (int t = 0; t < 4; ++t) {
    int idx = t * 512 + tid;
    int row = idx >> 3, c = idx & 7, gc = c ^ (row & 7);
    gA[t] = A + (size_t)(m0 + row) * K + gc * 8;
    lA[t] = idx * 16;
  }
  const unsigned short* gB[2]; int lB[2];
#pragma unroll
  for (int t = 0; t < 2; ++t) {
    int idx = t * 512 + tid;
    int row = idx >> 3, c = idx & 7, gc = c ^ (row & 7);
    gB[t] = Bw + (size_t)(n0 + row) * K + gc * 8;
    lB[t] = idx * 16;
  }
  // fragment read offsets (128-B rows, proven XOR swizzle)
  int oA[4][2], oB[4][2];
#pragma unroll
  for (int i = 0; i < 4; ++i)
#pragma unroll
    for (int ks = 0; ks < 2; ++ks) {
      int ra = wr * 64 + i * 16 + lane_r;
      oA[i][ks] = (ra * 128 + ks * 64 + lane_g * 16) ^ ((ra & 7) << 4);
      int rb = wc * 64 + i * 16 + lane_r;
      oB[i][ks] = (rb * 128 + ks * 64 + lane_g * 16) ^ ((rb & 7) << 4);
    }

  auto STAGE = [&](int kt, int bsel) {
    char* kd = smc + bsel * 49152;
    char* bd = kd + 32768;
#pragma unroll
    for (int t = 0; t < 4; ++t) GLOAD16(gA[t] + kt, kd + lA[t]);
#pragma unroll
    for (int t = 0; t < 2; ++t) GLOAD16(gB[t] + kt, bd + lB[t]);
  };

  const int NS = K >> 6;
  STAGE(0, 0);
  STAGE(64, 1);
#pragma unroll 1
  for (int s = 0; s < NS; ++s) {
    if (s + 1 < NS) asm volatile("s_waitcnt vmcnt(6)" ::: "memory");
    else            asm volatile("s_waitcnt vmcnt(0)" ::: "memory");
    __builtin_amdgcn_s_barrier();
    __builtin_amdgcn_sched_barrier(0);
    if (s + 2 < NS) STAGE((s + 2) * 64, (s + 2) % 3);
    const char* ab = smc + (s % 3) * 49152;
    const char* bb = ab + 32768;
    short8 af[4][2], bf[4][2];
#pragma unroll
    for (int i = 0; i < 4; ++i)
#pragma unroll
      for (int ks = 0; ks < 2; ++ks) {
        af[i][ks] = *(const short8*)(ab + oA[i][ks]);
        bf[i][ks] = *(const short8*)(bb + oB[i][ks]);
      }
    __builtin_amdgcn_s_setprio(1);
#pragma unroll
    for (int i = 0; i < 4; ++i)
#pragma unroll
      for (int j = 0; j < 4; ++j)
#pragma unroll
        for (int ks = 0; ks < 2; ++ks)
          acc[i][j] = __builtin_amdgcn_mfma_f32_16x16x32_bf16(af[i][ks], bf[j][ks], acc[i][j], 0, 0, 0);
    __builtin_amdgcn_s_setprio(0);
  }
  // epilogue: C row = (lane>>4)*4 + reg, col = lane&15 (verified layout)
#pragma unroll
  for (int i = 0; i < 4; ++i) {
    int row = m0 + wr * 64 + i * 16 + lane_g * 4;
#pragma unroll
    for (int j = 0; j < 4; ++j) {
      int col = n0 + wc * 64 + j * 16 + lane_r;
#pragma unroll
      for (int r = 0; r < 4; ++r) {
        float v = acc[i][j][r];
        if (OUTF)
          ((float*)Cp)[(size_t)(row + r) * N + col] = v;
        else
          ((unsigned short*)Cp)[(size_t)(row + r) * N + col] = f2bf(v);
      }
    }
  }
}

// ---------------- fused RMSNorm + RoPE (+qg, + score-scale fold for q) ------
__global__ __launch_bounds__(256) void normrope_kernel(unsigned short* __restrict__ qkv,
                                                       const float* __restrict__ cost,
                                                       const float* __restrict__ sint,
                                                       const float* __restrict__ qg) {
  const int tid = threadIdx.x, l = tid & 63, w = tid >> 6;
  int row = blockIdx.x * 4 + w;          // 0 .. 81919
  int tok = row / 20, hh = row - tok * 20;
  int t = tok & 2047;
  bool isq = hh < 16;
  int col0 = isq ? hh * 128 : 2048 + (hh - 16) * 128;
  unsigned short* p = qkv + (size_t)tok * 3072 + col0 + 2 * l;
  unsigned int u = *(const unsigned int*)p;
  float x0 = bf2f((unsigned short)(u & 0xffffu));
  float x1 = bf2f((unsigned short)(u >> 16));
  float ss = x0 * x0 + x1 * x1;
#pragma unroll
  for (int m = 1; m < 64; m <<= 1) ss += __shfl_xor(ss, m);
  float rn = rsqrtf(ss * (1.0f / 128.0f) + 1.1920928955078125e-07f);
  float n0 = x0 * rn, n1 = x1 * rn;
  float p0 = __shfl_xor(n0, 32);
  float p1 = __shfl_xor(n1, 32);
  int jj = (2 * l) & 63;
  float c0 = cost[t * 64 + jj], c1 = cost[t * 64 + jj + 1];
  float s0 = sint[t * 64 + jj], s1 = sint[t * 64 + jj + 1];
  float o0, o1;
  if (l < 32) { o0 = n0 * c0 + p0 * s0; o1 = n1 * c1 + p1 * s1; }
  else        { o0 = -p0 * s0 + n0 * c0; o1 = -p1 * s1 + n1 * c1; }
  if (isq) { float g = qg[hh] * 0.08838834764831845f; o0 *= g; o1 *= g; }
  *(unsigned int*)p = (unsigned)f2bf(o0) | ((unsigned)f2bf(o1) << 16);
}

// ---------------- V transpose: V[b][t][kvh][d] -> vtg[b*4+kvh][d][t] ----------
__global__ __launch_bounds__(256) void vtrans_kernel(const unsigned short* __restrict__ qkv,
                                                     unsigned short* __restrict__ vtg) {
  __shared__ unsigned short tile[64][132];   // [t][d], pad 4
  int bid = blockIdx.x;                      // 256 blocks
  int pan = bid & 7, tt = bid >> 3;          // pan = b*4+kvh, tt = t-tile
  int b = pan >> 2, kvh = pan & 3;
  int t0 = tt * 64;
  const unsigned short* src = qkv + ((size_t)(b * 2048 + t0)) * 3072 + 2560 + kvh * 128;
#pragma unroll
  for (int i = 0; i < 8; ++i) {
    int idx = i * 256 + threadIdx.x;         // 0..2047 uint2 loads
    int row = idx >> 5, c4 = idx & 31;
    uint2 v = *(const uint2*)(src + (size_t)row * 3072 + c4 * 4);
    *(uint2*)&tile[row][c4 * 4] = v;
  }
  __syncthreads();
  unsigned short* dst = vtg + (size_t)pan * 262144 + t0;
#pragma unroll
  for (int i = 0; i < 8; ++i) {
    int idx = i * 256 + threadIdx.x;
    int d = idx >> 4, tc = idx & 15;
    unsigned short a0 = tile[tc * 4 + 0][d], a1 = tile[tc * 4 + 1][d];
    unsigned short a2 = tile[tc * 4 + 2][d], a3 = tile[tc * 4 + 3][d];
    uint2 o; o.x = (unsigned)a0 | ((unsigned)a1 << 16);
    o.y = (unsigned)a2 | ((unsigned)a3 << 16);
    *(uint2*)(dst + (size_t)d * 2048 + tc * 4) = o;
  }
}

// ---------------- flash attention v4 (unchanged from R4) --------------------
__global__ __launch_bounds__(512) void attn_fa4(const unsigned short* __restrict__ qkv,
                                                const unsigned short* __restrict__ vtg,
                                                unsigned short* __restrict__ y) {
  extern __shared__ char smc[];
  const int tid = threadIdx.x;
  const int l = tid & 63, w = tid >> 6;
  const int lane_r = l & 15, lane_g = l >> 4;

  int n = blockIdx.x;
  int pan = n & 7;            // panel -> XCD (blockIdx%8 heuristic)
  int b = pan >> 2, kvh = pan & 3;
  int idx2 = n >> 3;
  int h = kvh * 4 + (idx2 & 3);
  int pairIdx = idx2 >> 2;    // 0..7
  const size_t rowbase = (size_t)b * 2048;
  const unsigned short* kvK = qkv + rowbase * 3072;
  const unsigned short* vtp = vtg + (size_t)pan * 262144;

  // staging descriptors
  int kg[2], vg[2], sl[2];
#pragma unroll
  for (int t = 0; t < 2; ++t) {
    int idx = t * 512 + tid;
    { int row = idx >> 4, c = idx & 15, gc = c ^ (row & 7);
      kg[t] = row * 3072 + 2048 + kvh * 128 + gc * 8; }
    { int d = idx >> 3, c = idx & 7, gc = c ^ (d & 7);
      vg[t] = d * 2048 + gc * 8; }
    sl[t] = idx * 16;
  }
  const int swz = (lane_r & 7) << 4;
  // K frag offsets: row = ct*16+lane_r (row stride 256B)
  int oK[4][4];
#pragma unroll
  for (int ct = 0; ct < 4; ++ct)
#pragma unroll
    for (int ks = 0; ks < 4; ++ks)
      oK[ct][ks] = ((ct * 16 + lane_r) * 256 + ks * 64 + lane_g * 16) ^ swz;
  // V^T frag offsets: row d = dt*16+lane_r (row stride 128B), rel to vbase
  int oV[2][8];
#pragma unroll
  for (int kk = 0; kk < 2; ++kk)
#pragma unroll
    for (int dt = 0; dt < 8; ++dt)
      oV[kk][dt] = ((dt * 16 + lane_r) * 128 + kk * 64 + lane_g * 16) ^ swz;
  // P offsets (wave-private [16 q][64 k] bf16, swizzled)
  const int pbase = 65536 + w * 2048;
  int pw_off[4];
#pragma unroll
  for (int ct = 0; ct < 4; ++ct)
    pw_off[ct] = pbase + lane_r * 128 + ((ct * 32 + lane_g * 8) ^ swz);
  int pr_off[2];
#pragma unroll
  for (int kk = 0; kk < 2; ++kk)
    pr_off[kk] = pbase + lane_r * 128 + ((kk * 64 + lane_g * 16) ^ swz);

  auto STAGE = [&](int tile, int bufsel) {
    const unsigned short* srcK = kvK + (size_t)tile * 64 * 3072;
    const unsigned short* srcV = vtp + tile * 64;
    char* kd = smc + bufsel * 16384;
    char* vd = smc + 32768 + bufsel * 16384;
#pragma unroll
    for (int t = 0; t < 2; ++t) {
      GLOAD16(srcK + kg[t], kd + sl[t]);
      GLOAD16(srcV + vg[t], vd + sl[t]);
    }
  };

#pragma unroll 1
  for (int phase = 0; phase < 2; ++phase) {
    const int qt = phase ? pairIdx : 15 - pairIdx;  // long tile first
    const int q0 = qt * 128;
    const int nkb = 2 * qt + 2;
    const int wrow0 = q0 + w * 16;
    const int qrow = wrow0 + lane_r;    // this lane's q row (all regs)

    STAGE(0, 0);
    short8 qf[4];
#pragma unroll
    for (int ks = 0; ks < 4; ++ks)
      qf[ks] = *(const short8*)(qkv + (rowbase + qrow) * 3072 + h * 128 + ks * 32 + lane_g * 8);

    f32x4 acc[8];
#pragma unroll
    for (int dt = 0; dt < 8; ++dt) acc[dt] = {0.f, 0.f, 0.f, 0.f};
    float mrun = -1e30f, lrun = 0.f;

    __syncthreads();   // tile 0 resident

#pragma unroll 1
    for (int kb = 0; kb < nkb; ++kb) {
      const int cur = kb & 1;
      if (kb + 1 < nkb) STAGE(kb + 1, cur ^ 1);   // prefetch overlaps compute
      const int j0 = kb * 64;
      const bool active = (j0 <= wrow0 + 15);
      if (active) {
        const int kbb = cur * 16384;
        // ---- S^T = K @ Q^T : S^T[k=ct*16+lane_g*4+r][q=lane_r] ----
        f32x4 s[4];
#pragma unroll
        for (int ct = 0; ct < 4; ++ct) s[ct] = {0.f, 0.f, 0.f, 0.f};
        __builtin_amdgcn_s_setprio(1);
#pragma unroll
        for (int ct = 0; ct < 4; ++ct)
#pragma unroll
          for (int ks = 0; ks < 4; ++ks) {
            short8 kf = *(const short8*)(smc + kbb + oK[ct][ks]);
            s[ct] = __builtin_amdgcn_mfma_f32_16x16x32_bf16(kf, qf[ks], s[ct], 0, 0, 0);
          }
        __builtin_amdgcn_s_setprio(0);
        // ---- causal mask (k = j0+ct*16+lane_g*4+r, q = qrow) ----
        if (j0 + 63 > wrow0) {
#pragma unroll
          for (int ct = 0; ct < 4; ++ct) {
            int kg0 = j0 + ct * 16 + lane_g * 4;
#pragma unroll
            for (int r = 0; r < 4; ++r)
              if (kg0 + r > qrow) s[ct][r] = -1e30f;
          }
        }
        // ---- online softmax (lane-local row) ----
        float mx = s[0][0];
#pragma unroll
        for (int ct = 0; ct < 4; ++ct)
#pragma unroll
          for (int r = 0; r < 4; ++r) mx = fmaxf(mx, s[ct][r]);
        mx = fmaxf(mx, __shfl_xor(mx, 16));
        mx = fmaxf(mx, __shfl_xor(mx, 32));
        float mn = fmaxf(mrun, mx);
        float corr = __expf(mrun - mn);
        mrun = mn;
        float rs = 0.f;
#pragma unroll
        for (int ct = 0; ct < 4; ++ct)
#pragma unroll
          for (int r = 0; r < 4; ++r) {
            float e = __expf(s[ct][r] - mn);
            s[ct][r] = e; rs += e;
          }
        rs += __shfl_xor(rs, 16);
        rs += __shfl_xor(rs, 32);
        lrun = lrun * corr + rs;
        // ---- P write (packed b64, swizzled) ----
#pragma unroll
        for (int ct = 0; ct < 4; ++ct) {
          uint2 pv;
          pv.x = (unsigned)f2bf(s[ct][0]) | ((unsigned)f2bf(s[ct][1]) << 16);
          pv.y = (unsigned)f2bf(s[ct][2]) | ((unsigned)f2bf(s[ct][3]) << 16);
          *(uint2*)(smc + pw_off[ct]) = pv;
        }
        // ---- rescale O ----
#pragma unroll
        for (int dt = 0; dt < 8; ++dt)
#pragma unroll
          for (int r = 0; r < 4; ++r) acc[dt][r] *= corr;
        // ---- O^T += V^T @ P^T ----
        short8 pf[2];
        pf[0] = *(const short8*)(smc + pr_off[0]);
        pf[1] = *(const short8*)(smc + pr_off[1]);
        const int vbase = 32768 + cur * 16384;
        __builtin_amdgcn_s_setprio(1);
#pragma unroll
        for (int kk = 0; kk < 2; ++kk)
#pragma unroll
          for (int dt = 0; dt < 8; ++dt) {
            short8 vf = *(const short8*)(smc + vbase + oV[kk][dt]);
            acc[dt] = __builtin_amdgcn_mfma_f32_16x16x32_bf16(vf, pf[kk], acc[dt], 0, 0, 0);
          }
        __builtin_amdgcn_s_setprio(0);
      }
      __syncthreads();   // prefetch drained; all waves done with cur bufs
    }
    // ---- epilogue: O^T[d=dt*16+lane_g*4+r][q=lane_r], pack 4 d per store ----
    float linv = 1.0f / lrun;
    unsigned short* yrow = y + (rowbase + qrow) * 2048 + h * 128;
#pragma unroll
    for (int dt = 0; dt < 8; ++dt) {
      uint2 o;
      o.x = (unsigned)f2bf(acc[dt][0] * linv) | ((unsigned)f2bf(acc[dt][1] * linv) << 16);
      o.y = (unsigned)f2bf(acc[dt][2] * linv) | ((unsigned)f2bf(acc[dt][3] * linv) << 16);
      *(uint2*)(yrow + dt * 16 + lane_g * 4) = o;
    }
  }
}

// ---------------- launch ----------------
extern "C" void kernel_launch(void* const* d_in, const int* in_sizes, int n_in,
                              void* d_out, int out_size, void* d_ws, size_t ws_size,
                              hipStream_t stream) {
  (void)in_sizes; (void)n_in; (void)out_size; (void)ws_size;
  const float* x  = (const float*)d_in[0];
  const float* qw = (const float*)d_in[1];
  const float* kw = (const float*)d_in[2];
  const float* vw = (const float*)d_in[3];
  const float* ow = (const float*)d_in[4];
  const float* qg = (const float*)d_in[5];

  char* ws = (char*)d_ws;
  unsigned short* xb   = (unsigned short*)(ws + 0);          // dead after gemm1
  unsigned short* vtg  = (unsigned short*)(ws + 0);          // aliases xb (4 MB)
  unsigned short* wqkv = (unsigned short*)(ws + 16777216);
  unsigned short* owb  = (unsigned short*)(ws + 29360128);
  unsigned short* qkvb = (unsigned short*)(ws + 37748736);
  unsigned short* y    = (unsigned short*)(ws + 62914560);
  float* cost          = (float*)(ws + 79691776);
  float* sint          = (float*)(ws + 80216064);

  prep_kernel<<<18944, 256, 0, stream>>>(x, qw, kw, vw, ow, xb, wqkv, owb, cost, sint);
  gemm_bt2<0><<<384, 512, 147456, stream>>>(xb, wqkv, qkvb, 16, 24, 3072, 2048);
  normrope_kernel<<<20480, 256, 0, stream>>>(qkvb, cost, sint, qg);
  vtrans_kernel<<<256, 256, 0, stream>>>(qkvb, vtg);
  attn_fa4<<<256, 512, 81920, stream>>>(qkvb, vtg, y);
  gemm_bt2<1><<<256, 512, 147456, stream>>>(y, owb, d_out, 16, 16, 2048, 2048);
}

// Round 6
// 200.406 us; speedup vs baseline: 2.2100x; 1.0697x over previous
//
#include <hip/hip_runtime.h>
#include <hip/hip_bf16.h>
#include <stdint.h>

// B=2, T=2048, D=2048, NH=16, NKV=4, HD=128.  qkv width = 3072 (q 0..2047, k 2048..2559, v 2560..3071)

typedef __attribute__((ext_vector_type(8))) short short8;
typedef __attribute__((ext_vector_type(4))) float f32x4;

#define GLOAD16(gp, lp) \
  __builtin_amdgcn_global_load_lds((const __attribute__((address_space(1))) void*)(gp), \
                                   (__attribute__((address_space(3))) void*)(lp), 16, 0, 0)

#define BAR() do { asm volatile("" ::: "memory"); __builtin_amdgcn_s_barrier(); asm volatile("" ::: "memory"); } while (0)

__device__ __forceinline__ float bf2f(unsigned short u) {
  union { unsigned int i; float f; } v; v.i = ((unsigned int)u) << 16; return v.f;
}
__device__ __forceinline__ unsigned short f2bf(float f) {
  union { float fl; unsigned int i; } v; v.fl = f;
  unsigned int r = v.i + 0x7fffu + ((v.i >> 16) & 1u);
  return (unsigned short)(r >> 16);
}

// ---------------- prep: f32->bf16 conversions + rope tables ----------------
__global__ __launch_bounds__(256) void prep_kernel(
    const float* __restrict__ x, const float* __restrict__ qw,
    const float* __restrict__ kw, const float* __restrict__ vw,
    const float* __restrict__ ow,
    unsigned short* __restrict__ xb, unsigned short* __restrict__ wqkv,
    unsigned short* __restrict__ owb, float* __restrict__ cost, float* __restrict__ sint) {
  const int NX = 2097152;   // x elems/4
  const int NW = 1572864;   // wqkv elems/4
  const int NO = 1048576;   // ow elems/4
  const int NT = 131072;    // table entries (2048*64)
  int tid = blockIdx.x * 256 + threadIdx.x;
  if (tid < NX) {
    float4 v = ((const float4*)x)[tid];
    uint2 o; o.x = (unsigned)f2bf(v.x) | ((unsigned)f2bf(v.y) << 16);
    o.y = (unsigned)f2bf(v.z) | ((unsigned)f2bf(v.w) << 16);
    ((uint2*)xb)[tid] = o;
  } else if (tid < NX + NW) {
    int i = tid - NX; int e = i * 4;
    const float* src = (e < 4194304) ? (qw + e)
                     : (e < 5242880) ? (kw + (e - 4194304))
                                     : (vw + (e - 5242880));
    float4 v = *(const float4*)src;
    uint2 o; o.x = (unsigned)f2bf(v.x) | ((unsigned)f2bf(v.y) << 16);
    o.y = (unsigned)f2bf(v.z) | ((unsigned)f2bf(v.w) << 16);
    ((uint2*)wqkv)[i] = o;
  } else if (tid < NX + NW + NO) {
    int i = tid - NX - NW;
    float4 v = ((const float4*)ow)[i];
    uint2 o; o.x = (unsigned)f2bf(v.x) | ((unsigned)f2bf(v.y) << 16);
    o.y = (unsigned)f2bf(v.z) | ((unsigned)f2bf(v.w) << 16);
    ((uint2*)owb)[i] = o;
  } else if (tid < NX + NW + NO + NT) {
    int i = tid - NX - NW - NO;
    int t = i >> 6, j = i & 63;
    // T(2048) > TSL(1024) branch: inv = 1/(10000 * 2^((128/126)^(j/64)))
    float e = exp2f(0.02272008f * (float)j * (1.0f / 64.0f));   // (128/126)^(j/64)
    float inv = 1.0f / (10000.0f * exp2f(e));
    float f = (float)t * inv;
    cost[i] = cosf(f);
    sint[i] = sinf(f);
  }
}

// ---------------- GEMM 8-phase: C = A @ Bw^T  (bf16 in, bf16/f32 out) -------
// BM = IM*32 (256 or 128), BN = 256, BK = 64. 8 waves as 2M x 4N; wave tile
// (IM*16) x 64. LDS: 2 dbuf x {A-chunk[ih] x2, B-chunk[jh] x2}; phase (ih,jh)
// reads exactly A[ih]+B[jh]. Staging at half-tile granularity 4-7 phases ahead:
// p0 -> A1(s+1), p1 -> A0(s+2), p2 -> B0(s+2), p3 -> B1(s+2); one counted
// vmcnt (6 / 5) per K-tile at p3 certifies the next tile's 4 halves; one raw
// s_barrier per phase. ds-reads per phase: 12 / 4 / 8 / 0. (T2+T3+T4+T5.)
template <int IM, int OUTF>
__global__ __launch_bounds__(512) void gemm8ph(const unsigned short* __restrict__ A,
                                               const unsigned short* __restrict__ Bw,
                                               void* __restrict__ Cp,
                                               int MT, int NTn, int N, int K) {
  extern __shared__ char smc[];
  constexpr int S = IM * 8;             // rows per (wr-band, ih) sub-band
  constexpr int IQ = IM / 2;            // i-frags per phase
  constexpr int ASZ = IM * 2048;        // bytes per A-chunk
  constexpr int DB = 2 * ASZ + 32768;   // dbuf stride
  constexpr int AL = (IM * 128) / 512;  // A gloads per thread per half (2 or 1)
  const int tid = threadIdx.x;
  const int l = tid & 63, w = tid >> 6;
  const int lane_r = l & 15, lane_g = l >> 4;
  const int wr = w >> 2, wc = w & 3;

  // bijective XCD swizzle (grid % 8 == 0); consecutive wgid share the A panel
  int qch = (MT * NTn) >> 3;
  int orig = blockIdx.x;
  int wgid = (orig & 7) * qch + (orig >> 3);
  int by = wgid / NTn, bx = wgid - by * NTn;
  const int m0 = by * IM * 32, n0 = bx * 256;

  f32x4 acc[IM][4];
#pragma unroll
  for (int i = 0; i < IM; ++i)
#pragma unroll
    for (int j = 0; j < 4; ++j) acc[i][j] = {0.f, 0.f, 0.f, 0.f};

  // staging descriptors (linear LDS dest, inverse-swizzled global source)
  const unsigned short* srcA[AL]; int ldA[AL];
#pragma unroll
  for (int t = 0; t < AL; ++t) {
    int idx = t * 512 + tid;
    int rc = idx >> 3, kc = idx & 7;
    int wrp = rc >= S ? 1 : 0, rr = rc & (S - 1);
    int row = wrp * 2 * S + rr;                 // ih*S added at call time
    srcA[t] = A + (size_t)(m0 + row) * K + (kc ^ (rc & 7)) * 8;
    ldA[t] = idx * 16;
  }
  const unsigned short* srcB[2]; int ldB[2];
#pragma unroll
  for (int t = 0; t < 2; ++t) {
    int idx = t * 512 + tid;
    int rc = idx >> 3, kc = idx & 7;
    int nrow = (rc >> 5) * 64 + (rc & 31);      // jh*32 added at call time
    srcB[t] = Bw + (size_t)(n0 + nrow) * K + (kc ^ (rc & 7)) * 8;
    ldB[t] = idx * 16;
  }
  const int SK = S * K, JK = 32 * K;

  auto STA = [&](int kt, int ih, int dqb) {
    char* d = smc + dqb + ih * ASZ;
#pragma unroll
    for (int t = 0; t < AL; ++t) GLOAD16(srcA[t] + kt + ih * SK, d + ldA[t]);
  };
  auto STB = [&](int kt, int jh, int dqb) {
    char* d = smc + dqb + 2 * ASZ + jh * 16384;
#pragma unroll
    for (int t = 0; t < 2; ++t) GLOAD16(srcB[t] + kt + jh * JK, d + ldB[t]);
  };

  // fragment read offsets (within a chunk; 128-B rows, proven XOR swizzle)
  int oA[IQ][2], oB[2][2];
#pragma unroll
  for (int iq = 0; iq < IQ; ++iq)
#pragma unroll
    for (int ks = 0; ks < 2; ++ks) {
      int rc = wr * S + iq * 16 + lane_r;
      oA[iq][ks] = rc * 128 + ((ks * 64 + lane_g * 16) ^ ((rc & 7) << 4));
    }
#pragma unroll
  for (int jj = 0; jj < 2; ++jj)
#pragma unroll
    for (int ks = 0; ks < 2; ++ks) {
      int rc = wc * 32 + jj * 16 + lane_r;
      oB[jj][ks] = rc * 128 + ((ks * 64 + lane_g * 16) ^ ((rc & 7) << 4));
    }

#define VMC() do { if constexpr (IM == 8) asm volatile("s_waitcnt vmcnt(6)" ::: "memory"); \
                   else                   asm volatile("s_waitcnt vmcnt(5)" ::: "memory"); } while (0)
#define VM0() asm volatile("s_waitcnt vmcnt(0)" ::: "memory")
#define MM(IH, JH, BR) do { \
    __builtin_amdgcn_s_setprio(1); \
    _Pragma("unroll") \
    for (int iq = 0; iq < IQ; ++iq) \
      _Pragma("unroll") \
      for (int jj = 0; jj < 2; ++jj) \
        _Pragma("unroll") \
        for (int ks = 0; ks < 2; ++ks) \
          acc[(IH) * IQ + iq][(JH) * 2 + jj] = __builtin_amdgcn_mfma_f32_16x16x32_bf16( \
              af[iq][ks], BR[jj][ks], acc[(IH) * IQ + iq][(JH) * 2 + jj], 0, 0, 0); \
    __builtin_amdgcn_s_setprio(0); } while (0)

  const int NS = K >> 6;
  // prologue: tile0 all 4 halves (oldest), then tile1 A0,B0,B1
  STA(0, 0, 0); STB(0, 0, 0); STB(0, 1, 0); STA(0, 1, 0);
  STA(64, 0, DB); STB(64, 0, DB); STB(64, 1, DB);
  VMC();
  BAR();

#pragma unroll 1
  for (int s = 0; s < NS; ++s) {
    const int dq = (s & 1) * DB, dn = DB - dq;
    const char* Ab = smc + dq;
    const char* Bb = Ab + 2 * ASZ;
    short8 af[IQ][2], b0[2][2], b1[2][2];
    // ---- phase 0: read A[0]+B[0], MFMA (ih0,jh0); stage A1(s+1) -> other buf
    if (s + 1 < NS) STA((s + 1) << 6, 1, dn);
#pragma unroll
    for (int iq = 0; iq < IQ; ++iq)
#pragma unroll
      for (int ks = 0; ks < 2; ++ks) af[iq][ks] = *(const short8*)(Ab + oA[iq][ks]);
#pragma unroll
    for (int jj = 0; jj < 2; ++jj)
#pragma unroll
      for (int ks = 0; ks < 2; ++ks) b0[jj][ks] = *(const short8*)(Bb + oB[jj][ks]);
    MM(0, 0, b0);
    BAR();
    // ---- phase 1: read B[1], MFMA (ih0,jh1); stage A0(s+2) -> this buf
    if (s + 2 < NS) STA((s + 2) << 6, 0, dq);
#pragma unroll
    for (int jj = 0; jj < 2; ++jj)
#pragma unroll
      for (int ks = 0; ks < 2; ++ks) b1[jj][ks] = *(const short8*)(Bb + 16384 + oB[jj][ks]);
    MM(0, 1, b1);
    BAR();
    // ---- phase 2: read A[1], MFMA (ih1,jh0); stage B0(s+2)
    if (s + 2 < NS) STB((s + 2) << 6, 0, dq);
#pragma unroll
    for (int iq = 0; iq < IQ; ++iq)
#pragma unroll
      for (int ks = 0; ks < 2; ++ks) af[iq][ks] = *(const short8*)(Ab + ASZ + oA[iq][ks]);
    MM(1, 0, b0);
    BAR();
    // ---- phase 3: MFMA (ih1,jh1); stage B1(s+2); counted vmcnt certifies tile s+1
    if (s + 2 < NS) STB((s + 2) << 6, 1, dq);
    MM(1, 1, b1);
    if (s + 2 < NS) VMC(); else VM0();
    BAR();
  }
#undef VMC
#undef VM0
#undef MM

  // epilogue: C row = (lane>>4)*4 + reg, col = lane&15 (verified layout)
#pragma unroll
  for (int ih = 0; ih < 2; ++ih)
#pragma unroll
    for (int iq = 0; iq < IQ; ++iq) {
      int row = m0 + wr * 2 * S + ih * S + iq * 16 + lane_g * 4;
#pragma unroll
      for (int j = 0; j < 4; ++j) {
        int col = n0 + wc * 64 + j * 16 + lane_r;
#pragma unroll
        for (int r = 0; r < 4; ++r) {
          float v = acc[ih * IQ + iq][j][r];
          if (OUTF)
            ((float*)Cp)[(size_t)(row + r) * N + col] = v;
          else
            ((unsigned short*)Cp)[(size_t)(row + r) * N + col] = f2bf(v);
        }
      }
    }
}

// ---------------- fused RMSNorm + RoPE (+qg, + score-scale fold for q) ------
__global__ __launch_bounds__(256) void normrope_kernel(unsigned short* __restrict__ qkv,
                                                       const float* __restrict__ cost,
                                                       const float* __restrict__ sint,
                                                       const float* __restrict__ qg) {
  const int tid = threadIdx.x, l = tid & 63, w = tid >> 6;
  int row = blockIdx.x * 4 + w;          // 0 .. 81919
  int tok = row / 20, hh = row - tok * 20;
  int t = tok & 2047;
  bool isq = hh < 16;
  int col0 = isq ? hh * 128 : 2048 + (hh - 16) * 128;
  unsigned short* p = qkv + (size_t)tok * 3072 + col0 + 2 * l;
  unsigned int u = *(const unsigned int*)p;
  float x0 = bf2f((unsigned short)(u & 0xffffu));
  float x1 = bf2f((unsigned short)(u >> 16));
  float ss = x0 * x0 + x1 * x1;
#pragma unroll
  for (int m = 1; m < 64; m <<= 1) ss += __shfl_xor(ss, m);
  float rn = rsqrtf(ss * (1.0f / 128.0f) + 1.1920928955078125e-07f);
  float n0 = x0 * rn, n1 = x1 * rn;
  float p0 = __shfl_xor(n0, 32);
  float p1 = __shfl_xor(n1, 32);
  int jj = (2 * l) & 63;
  float c0 = cost[t * 64 + jj], c1 = cost[t * 64 + jj + 1];
  float s0 = sint[t * 64 + jj], s1 = sint[t * 64 + jj + 1];
  float o0, o1;
  if (l < 32) { o0 = n0 * c0 + p0 * s0; o1 = n1 * c1 + p1 * s1; }
  else        { o0 = -p0 * s0 + n0 * c0; o1 = -p1 * s1 + n1 * c1; }
  if (isq) { float g = qg[hh] * 0.08838834764831845f; o0 *= g; o1 *= g; }
  *(unsigned int*)p = (unsigned)f2bf(o0) | ((unsigned)f2bf(o1) << 16);
}

// ---------------- V transpose: V[b][t][kvh][d] -> vtg[b*4+kvh][d][t] ----------
__global__ __launch_bounds__(256) void vtrans_kernel(const unsigned short* __restrict__ qkv,
                                                     unsigned short* __restrict__ vtg) {
  __shared__ unsigned short tile[64][132];   // [t][d], pad 4
  int bid = blockIdx.x;                      // 256 blocks
  int pan = bid & 7, tt = bid >> 3;          // pan = b*4+kvh, tt = t-tile
  int b = pan >> 2, kvh = pan & 3;
  int t0 = tt * 64;
  const unsigned short* src = qkv + ((size_t)(b * 2048 + t0)) * 3072 + 2560 + kvh * 128;
#pragma unroll
  for (int i = 0; i < 8; ++i) {
    int idx = i * 256 + threadIdx.x;         // 0..2047 uint2 loads
    int row = idx >> 5, c4 = idx & 31;
    uint2 v = *(const uint2*)(src + (size_t)row * 3072 + c4 * 4);
    *(uint2*)&tile[row][c4 * 4] = v;
  }
  __syncthreads();
  unsigned short* dst = vtg + (size_t)pan * 262144 + t0;
#pragma unroll
  for (int i = 0; i < 8; ++i) {
    int idx = i * 256 + threadIdx.x;
    int d = idx >> 4, tc = idx & 15;
    unsigned short a0 = tile[tc * 4 + 0][d], a1 = tile[tc * 4 + 1][d];
    unsigned short a2 = tile[tc * 4 + 2][d], a3 = tile[tc * 4 + 3][d];
    uint2 o; o.x = (unsigned)a0 | ((unsigned)a1 << 16);
    o.y = (unsigned)a2 | ((unsigned)a3 << 16);
    *(uint2*)(dst + (size_t)d * 2048 + tc * 4) = o;
  }
}

// ---------------- flash attention v4 (unchanged from R4/R5) -----------------
__global__ __launch_bounds__(512) void attn_fa4(const unsigned short* __restrict__ qkv,
                                                const unsigned short* __restrict__ vtg,
                                                unsigned short* __restrict__ y) {
  extern __shared__ char smc[];
  const int tid = threadIdx.x;
  const int l = tid & 63, w = tid >> 6;
  const int lane_r = l & 15, lane_g = l >> 4;

  int n = blockIdx.x;
  int pan = n & 7;            // panel -> XCD (blockIdx%8 heuristic)
  int b = pan >> 2, kvh = pan & 3;
  int idx2 = n >> 3;
  int h = kvh * 4 + (idx2 & 3);
  int pairIdx = idx2 >> 2;    // 0..7
  const size_t rowbase = (size_t)b * 2048;
  const unsigned short* kvK = qkv + rowbase * 3072;
  const unsigned short* vtp = vtg + (size_t)pan * 262144;

  // staging descriptors
  int kg[2], vg[2], sl[2];
#pragma unroll
  for (int t = 0; t < 2; ++t) {
    int idx = t * 512 + tid;
    { int row = idx >> 4, c = idx & 15, gc = c ^ (row & 7);
      kg[t] = row * 3072 + 2048 + kvh * 128 + gc * 8; }
    { int d = idx >> 3, c = idx & 7, gc = c ^ (d & 7);
      vg[t] = d * 2048 + gc * 8; }
    sl[t] = idx * 16;
  }
  const int swz = (lane_r & 7) << 4;
  // K frag offsets: row = ct*16+lane_r (row stride 256B)
  int oK[4][4];
#pragma unroll
  for (int ct = 0; ct < 4; ++ct)
#pragma unroll
    for (int ks = 0; ks < 4; ++ks)
      oK[ct][ks] = ((ct * 16 + lane_r) * 256 + ks * 64 + lane_g * 16) ^ swz;
  // V^T frag offsets: row d = dt*16+lane_r (row stride 128B), rel to vbase
  int oV[2][8];
#pragma unroll
  for (int kk = 0; kk < 2; ++kk)
#pragma unroll
    for (int dt = 0; dt < 8; ++dt)
      oV[kk][dt] = ((dt * 16 + lane_r) * 128 + kk * 64 + lane_g * 16) ^ swz;
  // P offsets (wave-private [16 q][64 k] bf16, swizzled)
  const int pbase = 65536 + w * 2048;
  int pw_off[4];
#pragma unroll
  for (int ct = 0; ct < 4; ++ct)
    pw_off[ct] = pbase + lane_r * 128 + ((ct * 32 + lane_g * 8) ^ swz);
  int pr_off[2];
#pragma unroll
  for (int kk = 0; kk < 2; ++kk)
    pr_off[kk] = pbase + lane_r * 128 + ((kk * 64 + lane_g * 16) ^ swz);

  auto STAGE = [&](int tile, int bufsel) {
    const unsigned short* srcK = kvK + (size_t)tile * 64 * 3072;
    const unsigned short* srcV = vtp + tile * 64;
    char* kd = smc + bufsel * 16384;
    char* vd = smc + 32768 + bufsel * 16384;
#pragma unroll
    for (int t = 0; t < 2; ++t) {
      GLOAD16(srcK + kg[t], kd + sl[t]);
      GLOAD16(srcV + vg[t], vd + sl[t]);
    }
  };

#pragma unroll 1
  for (int phase = 0; phase < 2; ++phase) {
    const int qt = phase ? pairIdx : 15 - pairIdx;  // long tile first
    const int q0 = qt * 128;
    const int nkb = 2 * qt + 2;
    const int wrow0 = q0 + w * 16;
    const int qrow = wrow0 + lane_r;    // this lane's q row (all regs)

    STAGE(0, 0);
    short8 qf[4];
#pragma unroll
    for (int ks = 0; ks < 4; ++ks)
      qf[ks] = *(const short8*)(qkv + (rowbase + qrow) * 3072 + h * 128 + ks * 32 + lane_g * 8);

    f32x4 acc[8];
#pragma unroll
    for (int dt = 0; dt < 8; ++dt) acc[dt] = {0.f, 0.f, 0.f, 0.f};
    float mrun = -1e30f, lrun = 0.f;

    __syncthreads();   // tile 0 resident

#pragma unroll 1
    for (int kb = 0; kb < nkb; ++kb) {
      const int cur = kb & 1;
      if (kb + 1 < nkb) STAGE(kb + 1, cur ^ 1);   // prefetch overlaps compute
      const int j0 = kb * 64;
      const bool active = (j0 <= wrow0 + 15);
      if (active) {
        const int kbb = cur * 16384;
        // ---- S^T = K @ Q^T : S^T[k=ct*16+lane_g*4+r][q=lane_r] ----
        f32x4 s[4];
#pragma unroll
        for (int ct = 0; ct < 4; ++ct) s[ct] = {0.f, 0.f, 0.f, 0.f};
        __builtin_amdgcn_s_setprio(1);
#pragma unroll
        for (int ct = 0; ct < 4; ++ct)
#pragma unroll
          for (int ks = 0; ks < 4; ++ks) {
            short8 kf = *(const short8*)(smc + kbb + oK[ct][ks]);
            s[ct] = __builtin_amdgcn_mfma_f32_16x16x32_bf16(kf, qf[ks], s[ct], 0, 0, 0);
          }
        __builtin_amdgcn_s_setprio(0);
        // ---- causal mask (k = j0+ct*16+lane_g*4+r, q = qrow) ----
        if (j0 + 63 > wrow0) {
#pragma unroll
          for (int ct = 0; ct < 4; ++ct) {
            int kg0 = j0 + ct * 16 + lane_g * 4;
#pragma unroll
            for (int r = 0; r < 4; ++r)
              if (kg0 + r > qrow) s[ct][r] = -1e30f;
          }
        }
        // ---- online softmax (lane-local row) ----
        float mx = s[0][0];
#pragma unroll
        for (int ct = 0; ct < 4; ++ct)
#pragma unroll
          for (int r = 0; r < 4; ++r) mx = fmaxf(mx, s[ct][r]);
        mx = fmaxf(mx, __shfl_xor(mx, 16));
        mx = fmaxf(mx, __shfl_xor(mx, 32));
        float mn = fmaxf(mrun, mx);
        float corr = __expf(mrun - mn);
        mrun = mn;
        float rs = 0.f;
#pragma unroll
        for (int ct = 0; ct < 4; ++ct)
#pragma unroll
          for (int r = 0; r < 4; ++r) {
            float e = __expf(s[ct][r] - mn);
            s[ct][r] = e; rs += e;
          }
        rs += __shfl_xor(rs, 16);
        rs += __shfl_xor(rs, 32);
        lrun = lrun * corr + rs;
        // ---- P write (packed b64, swizzled) ----
#pragma unroll
        for (int ct = 0; ct < 4; ++ct) {
          uint2 pv;
          pv.x = (unsigned)f2bf(s[ct][0]) | ((unsigned)f2bf(s[ct][1]) << 16);
          pv.y = (unsigned)f2bf(s[ct][2]) | ((unsigned)f2bf(s[ct][3]) << 16);
          *(uint2*)(smc + pw_off[ct]) = pv;
        }
        // ---- rescale O ----
#pragma unroll
        for (int dt = 0; dt < 8; ++dt)
#pragma unroll
          for (int r = 0; r < 4; ++r) acc[dt][r] *= corr;
        // ---- O^T += V^T @ P^T ----
        short8 pf[2];
        pf[0] = *(const short8*)(smc + pr_off[0]);
        pf[1] = *(const short8*)(smc + pr_off[1]);
        const int vbase = 32768 + cur * 16384;
        __builtin_amdgcn_s_setprio(1);
#pragma unroll
        for (int kk = 0; kk < 2; ++kk)
#pragma unroll
          for (int dt = 0; dt < 8; ++dt) {
            short8 vf = *(const short8*)(smc + vbase + oV[kk][dt]);
            acc[dt] = __builtin_amdgcn_mfma_f32_16x16x32_bf16(vf, pf[kk], acc[dt], 0, 0, 0);
          }
        __builtin_amdgcn_s_setprio(0);
      }
      __syncthreads();   // prefetch drained; all waves done with cur bufs
    }
    // ---- epilogue: O^T[d=dt*16+lane_g*4+r][q=lane_r], pack 4 d per store ----
    float linv = 1.0f / lrun;
    unsigned short* yrow = y + (rowbase + qrow) * 2048 + h * 128;
#pragma unroll
    for (int dt = 0; dt < 8; ++dt) {
      uint2 o;
      o.x = (unsigned)f2bf(acc[dt][0] * linv) | ((unsigned)f2bf(acc[dt][1] * linv) << 16);
      o.y = (unsigned)f2bf(acc[dt][2] * linv) | ((unsigned)f2bf(acc[dt][3] * linv) << 16);
      *(uint2*)(yrow + dt * 16 + lane_g * 4) = o;
    }
  }
}

// ---------------- launch ----------------
extern "C" void kernel_launch(void* const* d_in, const int* in_sizes, int n_in,
                              void* d_out, int out_size, void* d_ws, size_t ws_size,
                              hipStream_t stream) {
  (void)in_sizes; (void)n_in; (void)out_size; (void)ws_size;
  const float* x  = (const float*)d_in[0];
  const float* qw = (const float*)d_in[1];
  const float* kw = (const float*)d_in[2];
  const float* vw = (const float*)d_in[3];
  const float* ow = (const float*)d_in[4];
  const float* qg = (const float*)d_in[5];

  char* ws = (char*)d_ws;
  unsigned short* xb   = (unsigned short*)(ws + 0);          // dead after gemm1
  unsigned short* vtg  = (unsigned short*)(ws + 0);          // aliases xb (4 MB)
  unsigned short* wqkv = (unsigned short*)(ws + 16777216);
  unsigned short* owb  = (unsigned short*)(ws + 29360128);
  unsigned short* qkvb = (unsigned short*)(ws + 37748736);
  unsigned short* y    = (unsigned short*)(ws + 62914560);
  float* cost          = (float*)(ws + 79691776);
  float* sint          = (float*)(ws + 80216064);

  prep_kernel<<<18944, 256, 0, stream>>>(x, qw, kw, vw, ow, xb, wqkv, owb, cost, sint);
  gemm8ph<8, 0><<<192, 512, 131072, stream>>>(xb, wqkv, qkvb, 16, 12, 3072, 2048);
  normrope_kernel<<<20480, 256, 0, stream>>>(qkvb, cost, sint, qg);
  vtrans_kernel<<<256, 256, 0, stream>>>(qkvb, vtg);
  attn_fa4<<<256, 512, 81920, stream>>>(qkvb, vtg, y);
  gemm8ph<4, 1><<<256, 512, 98304, stream>>>(y, owb, d_out, 32, 8, 2048, 2048);
}